// Round 8
// baseline (685.255 us; speedup 1.0000x reference)
//
#include <hip/hip_runtime.h>
#include <cstdint>
#include <cstddef>
#include <math.h>

#define M_ROWS 16384
#define N_COLS 1000
#define N_PAD  1024
#define K_DIM  4096
#define NUM_TTA 64
#define KEPT 6
#define BATCH 256
#define CHUNK_MAX 16384
#define NKT (K_DIM / 32)       // 128 K-tiles of 32

typedef __attribute__((ext_vector_type(8))) short short8;
typedef __attribute__((ext_vector_type(16))) float v16f;

#define GL_LDS16(g, l)                                                        \
    __builtin_amdgcn_global_load_lds(                                         \
        (const __attribute__((address_space(1))) unsigned int*)(g),           \
        (__attribute__((address_space(3))) unsigned int*)(l), 16, 0, 0)

// ---- RNE bf16 split via HW cvt: x = hi + lo (+ ~2^-18 rel) ----
__device__ __forceinline__ void split2(float x, unsigned short& h, unsigned short& l) {
    const __bf16 hb = (__bf16)x;
    const float hf  = (float)hb;
    const __bf16 lb = (__bf16)(x - hf);
    h = __builtin_bit_cast(unsigned short, hb);
    l = __builtin_bit_cast(unsigned short, lb);
}

// 8 floats -> 8 hi bf16 + 8 lo bf16
__device__ __forceinline__ void split8(const float4& a, const float4& b,
                                       short8& hv, short8& lv) {
    unsigned short h, l;
    split2(a.x, h, l); hv[0] = (short)h; lv[0] = (short)l;
    split2(a.y, h, l); hv[1] = (short)h; lv[1] = (short)l;
    split2(a.z, h, l); hv[2] = (short)h; lv[2] = (short)l;
    split2(a.w, h, l); hv[3] = (short)h; lv[3] = (short)l;
    split2(b.x, h, l); hv[4] = (short)h; lv[4] = (short)l;
    split2(b.y, h, l); hv[5] = (short)h; lv[5] = (short)l;
    split2(b.z, h, l); hv[6] = (short)h; lv[6] = (short)l;
    split2(b.w, h, l); hv[7] = (short)h; lv[7] = (short)l;
}

// ---------------- W: transpose 4096x1000 -> [n][k] 1024x4096, split ----------------
__global__ __launch_bounds__(1024)
void split_w(const float* __restrict__ W, unsigned short* __restrict__ Wh,
             unsigned short* __restrict__ Wl)
{
    __shared__ float tile[32][33];
    const int k0 = blockIdx.x * 32, n0 = blockIdx.y * 32;
    const int tx = threadIdx.x, ty = threadIdx.y;
    const int n = n0 + tx, k = k0 + ty;
    tile[ty][tx] = (n < N_COLS) ? W[(size_t)k * N_COLS + n] : 0.f;
    __syncthreads();
    const float w = tile[tx][ty];           // = W[k0+tx][n0+ty]
    unsigned short h, l;
    split2(w, h, l);
    const size_t o = (size_t)(n0 + ty) * K_DIM + k0 + tx;
    Wh[o] = h; Wl[o] = l;
}

// ------------- GEMM: logits = X @ Wt^T + b via bf16 split-2 MFMA -------------
// 256x256 tile, 512 thr = 8 waves (2m x 4n), wave = 128x64 out, BK=32.
// Round-8 change: 32x32x16 MFMA shape (higher FLOP/pipe-cyc: 2495 vs 2075 TF
// ubench) -> per-tile MFMA floor 3725->3099 cyc, halved MFMA issue slots.
// LDS layout, staging, swizzle, barriers UNCHANGED (the chunk^((row>>1)&3)
// swizzle is conflict-free for the 32-row read pattern too).  Read addr:
// lane row = lane&31, k-half kq = lane>>5; kstep = addr XOR 0x20.
// C/D: col = lane&31, row = (reg&3)+8*(reg>>2)+4*(lane>>5)  [m74/m101].
__global__ __launch_bounds__(512, 2)
void gemm_mfma(const float* __restrict__ X,
               const unsigned short* __restrict__ Bh_, const unsigned short* __restrict__ Bl_,
               const float* __restrict__ bias, float* __restrict__ logits,
               int m_tiles)
{
    __shared__ __attribute__((aligned(16))) char smem[2 * 4 * 16384];

    const int t    = threadIdx.x;
    const int lane = t & 63;
    const int wave = t >> 6;
    const int wr   = wave >> 2;        // 0..1  m-half of block tile
    const int wc   = wave & 3;         // 0..3  n-quarter
    const int l31  = lane & 31;        // row/col within 32-tile
    const int kq   = lane >> 5;        // k-half (8 bf16 each) of the 16-k step

    // ---- XCD swizzle ----
    const int bid  = blockIdx.x;
    const int xcd  = bid & 7;
    const int slot = bid >> 3;
    const int mt   = xcd * (m_tiles >> 3) + (slot >> 2);
    const int nt   = slot & 3;
    const int m0 = mt * 256, n0 = nt * 256;

    // ---- B staging (global_load_lds, pre-swizzled source) ----
    const int    schunk = (t & 3) ^ ((t >> 3) & 3);
    const size_t ro     = (size_t)(t >> 2) * (K_DIM * 2) + (size_t)schunk * 16;
    const char* gBh = (const char*)Bh_ + (size_t)n0 * (K_DIM * 2) + ro;
    const char* gBl = (const char*)Bl_ + (size_t)n0 * (K_DIM * 2) + ro;
    char* ldst = smem + t * 16;
    const size_t RSTEP = (size_t)128 * K_DIM * 2;   // +128 rows

    // ---- A staging (reg path): thread t covers row ar, 16-float half ahalf ----
    const int ar    = t >> 1;          // 0..255
    const int ahalf = t & 1;           // k 0-15 or 16-31 within tile
    const float* gA = X + (size_t)(m0 + ar) * K_DIM + ahalf * 16;
    const int sigw = (ar >> 1) & 3;    // row swizzle key (matches reader)
    const int s0  = (ahalf * 2) ^ sigw;
    const int s1  = (ahalf * 2 + 1) ^ sigw;
    const int aw0 = ar * 64 + (s0 << 4);   // LDS byte off in A panel, floats 0-7
    const int aw1 = ar * 64 + (s1 << 4);   // floats 8-15

    // ---- per-lane LDS read bases (bytes within one 16KB mat panel) ----
    // row = base + l31; chunk c = kstep*2 + kq stored at slot c ^ ((row>>1)&3)
    const int sig  = (l31 >> 1) & 3;
    const int rdsw = ((kq ^ sig) & 3) << 4;        // kstep 0; kstep 1 = ^0x20
    const int lbA = wr * 8192 + l31 * 64 + rdsw;
    const int lbB = wc * 4096 + l31 * 64 + rdsw;

    v16f acc[4][2];
#pragma unroll
    for (int i = 0; i < 4; ++i)
#pragma unroll
        for (int j = 0; j < 2; ++j)
#pragma unroll
            for (int r = 0; r < 16; ++r) acc[i][j][r] = 0.f;

#define FRAG(P) (*(const short8*)(smem + (P)))
#define SB __builtin_amdgcn_sched_barrier(0)

    short8 ah[4], al[4], bh[2], bl[2];

    // ---------------- prologue: stage K-tile 0 into buf 0 ----------------
    {
        const float4 fa = *(const float4*)(gA);
        const float4 fb = *(const float4*)(gA + 4);
        const float4 fc = *(const float4*)(gA + 8);
        const float4 fd = *(const float4*)(gA + 12);
        GL_LDS16(gBh,         ldst + 32768);
        GL_LDS16(gBh + RSTEP, ldst + 40960);
        GL_LDS16(gBl,         ldst + 49152);
        GL_LDS16(gBl + RSTEP, ldst + 57344);
        short8 hv, lv;
        split8(fa, fb, hv, lv);
        *(short8*)(smem + aw0) = hv;
        *(short8*)(smem + 16384 + aw0) = lv;
        split8(fc, fd, hv, lv);
        *(short8*)(smem + aw1) = hv;
        *(short8*)(smem + 16384 + aw1) = lv;
    }
    __syncthreads();

// read all frags for one k-step (XO = 0 or 0x20)
#define RD_KS(XO) do {                                                        \
    bh[0] = FRAG((B0 + 32768 +        lbB) ^ (XO));                           \
    bl[0] = FRAG((B0 + 49152 +        lbB) ^ (XO));                           \
    bh[1] = FRAG((B0 + 32768 + 2048 + lbB) ^ (XO));                           \
    bl[1] = FRAG((B0 + 49152 + 2048 + lbB) ^ (XO));                           \
    _Pragma("unroll")                                                         \
    for (int mf = 0; mf < 4; ++mf) {                                          \
        ah[mf] = FRAG((B0 +         mf * 2048 + lbA) ^ (XO));                 \
        al[mf] = FRAG((B0 + 16384 + mf * 2048 + lbA) ^ (XO));                 \
    }                                                                         \
} while (0)
// 24 MFMA for one k-step: 3 passes x 8 independent accs (per-acc order kept)
#define MM_KS() do {                                                          \
    __builtin_amdgcn_s_setprio(1);                                            \
    _Pragma("unroll")                                                         \
    for (int mf = 0; mf < 4; ++mf)                                            \
        _Pragma("unroll")                                                     \
        for (int nf = 0; nf < 2; ++nf)                                        \
            acc[mf][nf] = __builtin_amdgcn_mfma_f32_32x32x16_bf16(ah[mf], bl[nf], acc[mf][nf], 0, 0, 0); \
    _Pragma("unroll")                                                         \
    for (int mf = 0; mf < 4; ++mf)                                            \
        _Pragma("unroll")                                                     \
        for (int nf = 0; nf < 2; ++nf)                                        \
            acc[mf][nf] = __builtin_amdgcn_mfma_f32_32x32x16_bf16(al[mf], bh[nf], acc[mf][nf], 0, 0, 0); \
    _Pragma("unroll")                                                         \
    for (int mf = 0; mf < 4; ++mf)                                            \
        _Pragma("unroll")                                                     \
        for (int nf = 0; nf < 2; ++nf)                                        \
            acc[mf][nf] = __builtin_amdgcn_mfma_f32_32x32x16_bf16(ah[mf], bh[nf], acc[mf][nf], 0, 0, 0); \
    __builtin_amdgcn_s_setprio(0);                                            \
} while (0)

#define TILE_BODY(KT, RB) do {                                                \
    const int B0 = (RB) * 65536;                                              \
    const int B1 = ((RB) ^ 1) * 65536;                                        \
    asm volatile("s_waitcnt vmcnt(0) lgkmcnt(0)" ::: "memory");               \
    __builtin_amdgcn_s_barrier();                                             \
    SB;                                                                       \
    const bool pf = (KT) + 1 < NKT;                                           \
    float4 fa, fb;                                                            \
    if (pf) {   /* issue next tile's loads early: A 8 floats + B GL_LDS */    \
        const float* ga_ = gA + ((KT) + 1) * 32;                              \
        fa = *(const float4*)(ga_);                                           \
        fb = *(const float4*)(ga_ + 4);                                       \
        const int kb_ = ((KT) + 1) * 64;                                      \
        GL_LDS16(gBh + kb_,         ldst + B1 + 32768);                       \
        GL_LDS16(gBh + RSTEP + kb_, ldst + B1 + 40960);                       \
        GL_LDS16(gBl + kb_,         ldst + B1 + 49152);                       \
        GL_LDS16(gBl + RSTEP + kb_, ldst + B1 + 57344);                       \
    }                                                                         \
    /* ---- k-step 0 ---- */                                                  \
    RD_KS(0); SB;                                                             \
    MM_KS(); SB;                                                              \
    if (pf) {   /* split floats 0-7 -> write; then load floats 8-15 */        \
        short8 hv, lv;                                                        \
        split8(fa, fb, hv, lv);                                               \
        *(short8*)(smem + B1 + aw0) = hv;                                     \
        *(short8*)(smem + B1 + 16384 + aw0) = lv;                             \
        const float* ga_ = gA + ((KT) + 1) * 32 + 8;                          \
        fa = *(const float4*)(ga_);                                           \
        fb = *(const float4*)(ga_ + 4);                                       \
    }                                                                         \
    SB;                                                                       \
    /* ---- k-step 1 (addr ^ 0x20); frag regs reused, WAR pinned ---- */      \
    RD_KS(0x20); SB;                                                          \
    MM_KS(); SB;                                                              \
    if (pf) {   /* split floats 8-15 -> write */                              \
        short8 hv, lv;                                                        \
        split8(fa, fb, hv, lv);                                               \
        *(short8*)(smem + B1 + aw1) = hv;                                     \
        *(short8*)(smem + B1 + 16384 + aw1) = lv;                             \
    }                                                                         \
} while (0)

#pragma unroll 1
    for (int kt = 0; kt < NKT; kt += 2) {
        TILE_BODY(kt, 0);
        TILE_BODY(kt + 1, 1);
    }

    // epilogue: 32x32 C/D: col = lane&31, row = (reg&3)+8*(reg>>2)+4*kq [m74/m101]
#pragma unroll
    for (int mf = 0; mf < 4; ++mf) {
        const int rbase = m0 + wr * 128 + mf * 32 + kq * 4;
#pragma unroll
        for (int nf = 0; nf < 2; ++nf) {
            const int col = n0 + wc * 64 + nf * 32 + l31;
            if (col < N_COLS) {
                const float bv = bias[col];
#pragma unroll
                for (int r = 0; r < 16; ++r) {
                    const int row = rbase + (r & 3) + 8 * (r >> 2);
                    logits[(size_t)row * N_COLS + col] = acc[mf][nf][r] + bv;
                }
            }
        }
    }
#undef TILE_BODY
#undef MM_KS
#undef RD_KS
#undef SB
#undef FRAG
}

// ---- inline f64 exp for d <= 0: rndne + 2-part ln2 + degree-12 Horner ----
__device__ __forceinline__ double exp_neg(double d) {
    if (d < -700.0) return 0.0;
    const double kd = rint(d * 1.4426950408889634074);
    double r = fma(-kd, 6.93147180369123816490e-01, d);
    r = fma(-kd, 1.90821492927058770002e-10, r);
    double p = 2.08767569878680989792e-09;      // 1/12!
    p = fma(p, r, 2.50521083854417187751e-08);  // 1/11!
    p = fma(p, r, 2.75573192239858906526e-07);  // 1/10!
    p = fma(p, r, 2.75573192239858925110e-06);  // 1/9!
    p = fma(p, r, 2.48015873015873015873e-05);  // 1/8!
    p = fma(p, r, 1.98412698412698412526e-04);  // 1/7!
    p = fma(p, r, 1.38888888888888894069e-03);  // 1/6!
    p = fma(p, r, 8.33333333333333321769e-03);  // 1/5!
    p = fma(p, r, 4.16666666666666643537e-02);  // 1/4!
    p = fma(p, r, 1.66666666666666657415e-01);  // 1/3!
    p = fma(p, r, 5.0e-01);
    p = fma(p, r, 1.0);
    p = fma(p, r, 1.0);
    const long long k = (long long)kd;
    return p * __longlong_as_double((1023LL + k) << 52);
}

// ------------- per-view softmax stats: entropy (f64 accum) + argmax -------------
// 1 wave per row, 4 rows per block; row held in 16 VGPR; shuffle reductions.
__global__ __launch_bounds__(256)
void row_stats(const float* __restrict__ logits, double* __restrict__ ent,
               int* __restrict__ votes, int v_base)
{
    const int lane = threadIdx.x & 63;
    const int wave = threadIdx.x >> 6;
    const int row  = blockIdx.x * 4 + wave;
    const float* rp = logits + (size_t)row * N_COLS;

    float v[16];
    float bv = -3.0e38f; int bi = 0;
#pragma unroll
    for (int j = 0; j < 16; ++j) {
        const int c = j * 64 + lane;
        const float x = (c < N_COLS) ? rp[c] : -3.0e38f;
        v[j] = x;
        if (x > bv) { bv = x; bi = c; }
    }
#pragma unroll
    for (int s = 32; s > 0; s >>= 1) {
        const float ov = __shfl_xor(bv, s);
        const int   oi = __shfl_xor(bi, s);
        if (ov > bv || (ov == bv && oi < bi)) { bv = ov; bi = oi; }
    }
    const float mx = bv;
    const int amax = bi;

    double S = 0.0, T = 0.0;
#pragma unroll
    for (int j = 0; j < 16; ++j) {
        const int c = j * 64 + lane;
        if (c < N_COLS) {
            const float d = v[j] - mx;
            const double e = exp_neg((double)d);
            S += e; T += e * (double)d;
        }
    }
#pragma unroll
    for (int s = 32; s > 0; s >>= 1) {
        S += __shfl_xor(S, s);
        T += __shfl_xor(T, s);
    }
    if (lane == 0) {
        ent[v_base + row]   = log(S) - T / S;
        votes[v_base + row] = amax;
    }
}

// ------------- per-batch voting: stable sort by entropy, tie loop -------------
__global__ __launch_bounds__(64)
void vote_kernel(const double* __restrict__ ent, const int* __restrict__ votes,
                 float* __restrict__ out)
{
    __shared__ double e[NUM_TTA];
    __shared__ int    sv[NUM_TTA];
    __shared__ float  counts[N_COLS];

    const int b = blockIdx.x;
    const int t = threadIdx.x;

    e[t] = ent[b * NUM_TTA + t];
    const int myv = votes[b * NUM_TTA + t];
    for (int c = t; c < N_COLS; c += NUM_TTA) counts[c] = 0.f;
    __syncthreads();

    const double et = e[t];
    int rank = 0;
#pragma unroll
    for (int i = 0; i < NUM_TTA; ++i) {
        const double ei = e[i];
        rank += (ei < et) || (ei == et && i < t);
    }
    sv[rank] = myv;
    __syncthreads();

    if (t == 0) {
        for (int j = 0; j < KEPT; ++j) counts[sv[j]] += 1.f;
        float Mv = 0.f; int Tc = 0;
        for (int j = 0; j < KEPT; ++j) {
            const int c = sv[j];
            bool dup = false;
            for (int q = 0; q < j; ++q) dup = dup || (sv[q] == c);
            if (dup) continue;
            const float cv = counts[c];
            if (cv > Mv) { Mv = cv; Tc = 1; }
            else if (cv == Mv) { Tc += 1; }
        }
        for (int i = 0; i < NUM_TTA - KEPT; ++i) {
            if (Tc <= 1) break;
            const int c = sv[KEPT + i];
            const float oldc = counts[c];
            counts[c] = oldc + 1.f;
            if (oldc == Mv)            { Mv += 1.f; Tc = 1; }
            else if (oldc + 1.f == Mv) { Tc += 1; }
        }
    }
    __syncthreads();

    const size_t o0 = (size_t)b * N_COLS;
    for (int c = t; c < N_COLS; c += NUM_TTA)
        out[o0 + c] = logf(counts[c] * (1.f / 64.f) + 1e-8f);
}

// -------------------------------- launch --------------------------------
extern "C" void kernel_launch(void* const* d_in, const int* in_sizes, int n_in,
                              void* d_out, int out_size, void* d_ws, size_t ws_size,
                              hipStream_t stream) {
    const float* x    = (const float*)d_in[0];
    const float* Wm   = (const float*)d_in[1];
    const float* bias = (const float*)d_in[2];
    float* out = (float*)d_out;

    // ws layout: ent f64[16384] | votes i32[16384] | Wh,Wl bf16[1024*4096]
    //            | per-chunk logits f32[R*1000]   (A split fused in GEMM)
    char* p = (char*)d_ws;
    double* ent  = (double*)p;                     p += (size_t)M_ROWS * 8;
    int*   votes = (int*)p;                        p += (size_t)M_ROWS * 4;
    unsigned short* Wh = (unsigned short*)p;       p += (size_t)N_PAD * K_DIM * 2;
    unsigned short* Wl = (unsigned short*)p;       p += (size_t)N_PAD * K_DIM * 2;
    const size_t base = (size_t)(p - (char*)d_ws);

    // R: rows per chunk, multiple of 2048 so m_tiles (rows/256) is divisible by 8
    long long R = 0;
    if (ws_size > base) R = (long long)((ws_size - base) / (size_t)4000);
    R = (R / 2048) * 2048;
    if (R > CHUNK_MAX) R = CHUNK_MAX;
    if (R < 2048) R = 2048;

    float* logits = (float*)p;

    split_w<<<dim3(K_DIM / 32, N_PAD / 32), dim3(32, 32), 0, stream>>>(Wm, Wh, Wl);

    for (int m0 = 0; m0 < M_ROWS; m0 += (int)R) {
        const int rows = (int)(((long long)(M_ROWS - m0) < R) ? (M_ROWS - m0) : R);
        const int m_tiles = rows / 256;
        gemm_mfma<<<4 * m_tiles, 512, 0, stream>>>(
            x + (size_t)m0 * K_DIM, Wh, Wl, bias, logits, m_tiles);
        row_stats<<<rows / 4, 256, 0, stream>>>(logits, ent, votes, m0);
    }
    vote_kernel<<<BATCH, NUM_TTA, 0, stream>>>(ent, votes, out);
}

// Round 9
// 679.755 us; speedup vs baseline: 1.0081x; 1.0081x over previous
//
#include <hip/hip_runtime.h>
#include <cstdint>
#include <cstddef>
#include <math.h>

#define M_ROWS 16384
#define N_COLS 1000
#define N_PAD  1024
#define K_DIM  4096
#define NUM_TTA 64
#define KEPT 6
#define BATCH 256
#define CHUNK_MAX 16384
#define NKT (K_DIM / 32)       // 128 K-tiles of 32

typedef __attribute__((ext_vector_type(8))) short short8;
typedef __attribute__((ext_vector_type(16))) float v16f;

#define GL_LDS16(g, l)                                                        \
    __builtin_amdgcn_global_load_lds(                                         \
        (const __attribute__((address_space(1))) unsigned int*)(g),           \
        (__attribute__((address_space(3))) unsigned int*)(l), 16, 0, 0)

// ---- RNE bf16 split via HW cvt: x = hi + lo (+ ~2^-18 rel) ----
__device__ __forceinline__ void split2(float x, unsigned short& h, unsigned short& l) {
    const __bf16 hb = (__bf16)x;
    const float hf  = (float)hb;
    const __bf16 lb = (__bf16)(x - hf);
    h = __builtin_bit_cast(unsigned short, hb);
    l = __builtin_bit_cast(unsigned short, lb);
}

// 8 floats -> 8 hi bf16 + 8 lo bf16
__device__ __forceinline__ void split8(const float4& a, const float4& b,
                                       short8& hv, short8& lv) {
    unsigned short h, l;
    split2(a.x, h, l); hv[0] = (short)h; lv[0] = (short)l;
    split2(a.y, h, l); hv[1] = (short)h; lv[1] = (short)l;
    split2(a.z, h, l); hv[2] = (short)h; lv[2] = (short)l;
    split2(a.w, h, l); hv[3] = (short)h; lv[3] = (short)l;
    split2(b.x, h, l); hv[4] = (short)h; lv[4] = (short)l;
    split2(b.y, h, l); hv[5] = (short)h; lv[5] = (short)l;
    split2(b.z, h, l); hv[6] = (short)h; lv[6] = (short)l;
    split2(b.w, h, l); hv[7] = (short)h; lv[7] = (short)l;
}

// ---------------- W: transpose 4096x1000 -> [n][k] 1024x4096, split ----------------
__global__ __launch_bounds__(1024)
void split_w(const float* __restrict__ W, unsigned short* __restrict__ Wh,
             unsigned short* __restrict__ Wl)
{
    __shared__ float tile[32][33];
    const int k0 = blockIdx.x * 32, n0 = blockIdx.y * 32;
    const int tx = threadIdx.x, ty = threadIdx.y;
    const int n = n0 + tx, k = k0 + ty;
    tile[ty][tx] = (n < N_COLS) ? W[(size_t)k * N_COLS + n] : 0.f;
    __syncthreads();
    const float w = tile[tx][ty];           // = W[k0+tx][n0+ty]
    unsigned short h, l;
    split2(w, h, l);
    const size_t o = (size_t)(n0 + ty) * K_DIM + k0 + tx;
    Wh[o] = h; Wl[o] = l;
}

// ------------- GEMM: logits = X @ Wt^T + b via bf16 split-2 MFMA -------------
// 256x256 tile, 512 thr = 8 waves (2m x 4n), wave = 128x64 out, BK=32,
// 32x32x16 MFMA.  Round-9 change: chunk->slot map  slot = beta(c) ^ g(r),
// beta = (0,3,2,1), g(r) = ((r>>1)^(r>>3))&3.  Conflict-free under ALL
// plausible LDS phase groupings ({l,+8},{l,+16},{l,+32},consecutive-8) for
// both reads and writes -- fixes r8's 2.5e7 bank conflicts (lanes l / l+32
// read same row with slots differing in bit 0 under the old map).
// kstep1 = addr XOR 0x20 still holds (beta maps {0,1}->{0,3}, {2,3}->{2,1}).
// C/D: col = lane&31, row = (reg&3)+8*(reg>>2)+4*(lane>>5)  [m74/m101].
__global__ __launch_bounds__(512, 2)
void gemm_mfma(const float* __restrict__ X,
               const unsigned short* __restrict__ Bh_, const unsigned short* __restrict__ Bl_,
               const float* __restrict__ bias, float* __restrict__ logits,
               int m_tiles)
{
    __shared__ __attribute__((aligned(16))) char smem[2 * 4 * 16384];

    const int t    = threadIdx.x;
    const int lane = t & 63;
    const int wave = t >> 6;
    const int wr   = wave >> 2;        // 0..1  m-half of block tile
    const int wc   = wave & 3;         // 0..3  n-quarter
    const int l31  = lane & 31;        // row/col within 32-tile
    const int kq   = lane >> 5;        // k-half (8 bf16 each) of the 16-k step

    // ---- XCD swizzle ----
    const int bid  = blockIdx.x;
    const int xcd  = bid & 7;
    const int slot = bid >> 3;
    const int mt   = xcd * (m_tiles >> 3) + (slot >> 2);
    const int nt   = slot & 3;
    const int m0 = mt * 256, n0 = nt * 256;

    // ---- B staging (global_load_lds, pre-swizzled source) ----
    // thread t covers LDS slot s=t&3 of row r=t>>2; loads chunk beta(s^g(r)).
    const int sx     = (t & 3) ^ ((t >> 3) & 3) ^ ((t >> 5) & 3);
    const int schunk = sx ^ ((sx & 1) << 1);            // beta(sx)
    const size_t ro     = (size_t)(t >> 2) * (K_DIM * 2) + (size_t)schunk * 16;
    const char* gBh = (const char*)Bh_ + (size_t)n0 * (K_DIM * 2) + ro;
    const char* gBl = (const char*)Bl_ + (size_t)n0 * (K_DIM * 2) + ro;
    char* ldst = smem + t * 16;
    const size_t RSTEP = (size_t)128 * K_DIM * 2;   // +128 rows

    // ---- A staging (reg path): thread t covers row ar, 16-float half ahalf ----
    const int ar    = t >> 1;          // 0..255
    const int ahalf = t & 1;           // k 0-15 or 16-31 within tile
    const float* gA = X + (size_t)(m0 + ar) * K_DIM + ahalf * 16;
    const int gw  = ((ar >> 1) ^ (ar >> 3)) & 3;        // g(row) for writer
    const int s0  = (ahalf << 1) ^ gw;                  // slot of chunk 2*ahalf
    const int s1  = s0 ^ 3;                             // slot of chunk 2*ahalf+1
    const int aw0 = ar * 64 + (s0 << 4);   // LDS byte off in A panel, floats 0-7
    const int aw1 = ar * 64 + (s1 << 4);   // floats 8-15

    // ---- per-lane LDS read bases (bytes within one 16KB mat panel) ----
    // kstep0 chunk = kq -> slot beta(kq)^g = (3*kq)^g ; kstep1 = addr ^ 0x20
    const int gl   = ((l31 >> 1) ^ (l31 >> 3)) & 3;
    const int rdsw = ((3 * kq) ^ gl) << 4;
    const int lbA = wr * 8192 + l31 * 64 + rdsw;
    const int lbB = wc * 4096 + l31 * 64 + rdsw;

    v16f acc[4][2];
#pragma unroll
    for (int i = 0; i < 4; ++i)
#pragma unroll
        for (int j = 0; j < 2; ++j)
#pragma unroll
            for (int r = 0; r < 16; ++r) acc[i][j][r] = 0.f;

#define FRAG(P) (*(const short8*)(smem + (P)))
#define SB __builtin_amdgcn_sched_barrier(0)

    short8 ah[4], al[4], bh[2], bl[2];

    // ---------------- prologue: stage K-tile 0 into buf 0 ----------------
    {
        const float4 fa = *(const float4*)(gA);
        const float4 fb = *(const float4*)(gA + 4);
        const float4 fc = *(const float4*)(gA + 8);
        const float4 fd = *(const float4*)(gA + 12);
        GL_LDS16(gBh,         ldst + 32768);
        GL_LDS16(gBh + RSTEP, ldst + 40960);
        GL_LDS16(gBl,         ldst + 49152);
        GL_LDS16(gBl + RSTEP, ldst + 57344);
        short8 hv, lv;
        split8(fa, fb, hv, lv);
        *(short8*)(smem + aw0) = hv;
        *(short8*)(smem + 16384 + aw0) = lv;
        split8(fc, fd, hv, lv);
        *(short8*)(smem + aw1) = hv;
        *(short8*)(smem + 16384 + aw1) = lv;
    }
    __syncthreads();

// read all frags for one k-step (XO = 0 or 0x20)
#define RD_KS(XO) do {                                                        \
    bh[0] = FRAG((B0 + 32768 +        lbB) ^ (XO));                           \
    bl[0] = FRAG((B0 + 49152 +        lbB) ^ (XO));                           \
    bh[1] = FRAG((B0 + 32768 + 2048 + lbB) ^ (XO));                           \
    bl[1] = FRAG((B0 + 49152 + 2048 + lbB) ^ (XO));                           \
    _Pragma("unroll")                                                         \
    for (int mf = 0; mf < 4; ++mf) {                                          \
        ah[mf] = FRAG((B0 +         mf * 2048 + lbA) ^ (XO));                 \
        al[mf] = FRAG((B0 + 16384 + mf * 2048 + lbA) ^ (XO));                 \
    }                                                                         \
} while (0)
// 24 MFMA for one k-step: 3 passes x 8 independent accs (per-acc order kept)
#define MM_KS() do {                                                          \
    __builtin_amdgcn_s_setprio(1);                                            \
    _Pragma("unroll")                                                         \
    for (int mf = 0; mf < 4; ++mf)                                            \
        _Pragma("unroll")                                                     \
        for (int nf = 0; nf < 2; ++nf)                                        \
            acc[mf][nf] = __builtin_amdgcn_mfma_f32_32x32x16_bf16(ah[mf], bl[nf], acc[mf][nf], 0, 0, 0); \
    _Pragma("unroll")                                                         \
    for (int mf = 0; mf < 4; ++mf)                                            \
        _Pragma("unroll")                                                     \
        for (int nf = 0; nf < 2; ++nf)                                        \
            acc[mf][nf] = __builtin_amdgcn_mfma_f32_32x32x16_bf16(al[mf], bh[nf], acc[mf][nf], 0, 0, 0); \
    _Pragma("unroll")                                                         \
    for (int mf = 0; mf < 4; ++mf)                                            \
        _Pragma("unroll")                                                     \
        for (int nf = 0; nf < 2; ++nf)                                        \
            acc[mf][nf] = __builtin_amdgcn_mfma_f32_32x32x16_bf16(ah[mf], bh[nf], acc[mf][nf], 0, 0, 0); \
    __builtin_amdgcn_s_setprio(0);                                            \
} while (0)

#define TILE_BODY(KT, RB) do {                                                \
    const int B0 = (RB) * 65536;                                              \
    const int B1 = ((RB) ^ 1) * 65536;                                        \
    asm volatile("s_waitcnt vmcnt(0) lgkmcnt(0)" ::: "memory");               \
    __builtin_amdgcn_s_barrier();                                             \
    SB;                                                                       \
    const bool pf = (KT) + 1 < NKT;                                           \
    float4 fa, fb;                                                            \
    if (pf) {   /* issue next tile's loads early: A 8 floats + B GL_LDS */    \
        const float* ga_ = gA + ((KT) + 1) * 32;                              \
        fa = *(const float4*)(ga_);                                           \
        fb = *(const float4*)(ga_ + 4);                                       \
        const int kb_ = ((KT) + 1) * 64;                                      \
        GL_LDS16(gBh + kb_,         ldst + B1 + 32768);                       \
        GL_LDS16(gBh + RSTEP + kb_, ldst + B1 + 40960);                       \
        GL_LDS16(gBl + kb_,         ldst + B1 + 49152);                       \
        GL_LDS16(gBl + RSTEP + kb_, ldst + B1 + 57344);                       \
    }                                                                         \
    /* ---- k-step 0 ---- */                                                  \
    RD_KS(0); SB;                                                             \
    MM_KS(); SB;                                                              \
    if (pf) {   /* split floats 0-7 -> write; then load floats 8-15 */        \
        short8 hv, lv;                                                        \
        split8(fa, fb, hv, lv);                                               \
        *(short8*)(smem + B1 + aw0) = hv;                                     \
        *(short8*)(smem + B1 + 16384 + aw0) = lv;                             \
        const float* ga_ = gA + ((KT) + 1) * 32 + 8;                          \
        fa = *(const float4*)(ga_);                                           \
        fb = *(const float4*)(ga_ + 4);                                       \
    }                                                                         \
    SB;                                                                       \
    /* ---- k-step 1 (addr ^ 0x20); frag regs reused, WAR pinned ---- */      \
    RD_KS(0x20); SB;                                                          \
    MM_KS(); SB;                                                              \
    if (pf) {   /* split floats 8-15 -> write */                              \
        short8 hv, lv;                                                        \
        split8(fa, fb, hv, lv);                                               \
        *(short8*)(smem + B1 + aw1) = hv;                                     \
        *(short8*)(smem + B1 + 16384 + aw1) = lv;                             \
    }                                                                         \
} while (0)

#pragma unroll 1
    for (int kt = 0; kt < NKT; kt += 2) {
        TILE_BODY(kt, 0);
        TILE_BODY(kt + 1, 1);
    }

    // epilogue: 32x32 C/D: col = lane&31, row = (reg&3)+8*(reg>>2)+4*kq [m74/m101]
#pragma unroll
    for (int mf = 0; mf < 4; ++mf) {
        const int rbase = m0 + wr * 128 + mf * 32 + kq * 4;
#pragma unroll
        for (int nf = 0; nf < 2; ++nf) {
            const int col = n0 + wc * 64 + nf * 32 + l31;
            if (col < N_COLS) {
                const float bv = bias[col];
#pragma unroll
                for (int r = 0; r < 16; ++r) {
                    const int row = rbase + (r & 3) + 8 * (r >> 2);
                    logits[(size_t)row * N_COLS + col] = acc[mf][nf][r] + bv;
                }
            }
        }
    }
#undef TILE_BODY
#undef MM_KS
#undef RD_KS
#undef SB
#undef FRAG
}

// ---- inline f64 exp for d <= 0: rndne + 2-part ln2 + degree-12 Horner ----
__device__ __forceinline__ double exp_neg(double d) {
    if (d < -700.0) return 0.0;
    const double kd = rint(d * 1.4426950408889634074);
    double r = fma(-kd, 6.93147180369123816490e-01, d);
    r = fma(-kd, 1.90821492927058770002e-10, r);
    double p = 2.08767569878680989792e-09;      // 1/12!
    p = fma(p, r, 2.50521083854417187751e-08);  // 1/11!
    p = fma(p, r, 2.75573192239858906526e-07);  // 1/10!
    p = fma(p, r, 2.75573192239858925110e-06);  // 1/9!
    p = fma(p, r, 2.48015873015873015873e-05);  // 1/8!
    p = fma(p, r, 1.98412698412698412526e-04);  // 1/7!
    p = fma(p, r, 1.38888888888888894069e-03);  // 1/6!
    p = fma(p, r, 8.33333333333333321769e-03);  // 1/5!
    p = fma(p, r, 4.16666666666666643537e-02);  // 1/4!
    p = fma(p, r, 1.66666666666666657415e-01);  // 1/3!
    p = fma(p, r, 5.0e-01);
    p = fma(p, r, 1.0);
    p = fma(p, r, 1.0);
    const long long k = (long long)kd;
    return p * __longlong_as_double((1023LL + k) << 52);
}

// ------------- per-view softmax stats: entropy (f64 accum) + argmax -------------
// 1 wave per row, 4 rows per block; row held in 16 VGPR; shuffle reductions.
__global__ __launch_bounds__(256)
void row_stats(const float* __restrict__ logits, double* __restrict__ ent,
               int* __restrict__ votes, int v_base)
{
    const int lane = threadIdx.x & 63;
    const int wave = threadIdx.x >> 6;
    const int row  = blockIdx.x * 4 + wave;
    const float* rp = logits + (size_t)row * N_COLS;

    float v[16];
    float bv = -3.0e38f; int bi = 0;
#pragma unroll
    for (int j = 0; j < 16; ++j) {
        const int c = j * 64 + lane;
        const float x = (c < N_COLS) ? rp[c] : -3.0e38f;
        v[j] = x;
        if (x > bv) { bv = x; bi = c; }
    }
#pragma unroll
    for (int s = 32; s > 0; s >>= 1) {
        const float ov = __shfl_xor(bv, s);
        const int   oi = __shfl_xor(bi, s);
        if (ov > bv || (ov == bv && oi < bi)) { bv = ov; bi = oi; }
    }
    const float mx = bv;
    const int amax = bi;

    double S = 0.0, T = 0.0;
#pragma unroll
    for (int j = 0; j < 16; ++j) {
        const int c = j * 64 + lane;
        if (c < N_COLS) {
            const float d = v[j] - mx;
            const double e = exp_neg((double)d);
            S += e; T += e * (double)d;
        }
    }
#pragma unroll
    for (int s = 32; s > 0; s >>= 1) {
        S += __shfl_xor(S, s);
        T += __shfl_xor(T, s);
    }
    if (lane == 0) {
        ent[v_base + row]   = log(S) - T / S;
        votes[v_base + row] = amax;
    }
}

// ------------- per-batch voting: stable sort by entropy, tie loop -------------
__global__ __launch_bounds__(64)
void vote_kernel(const double* __restrict__ ent, const int* __restrict__ votes,
                 float* __restrict__ out)
{
    __shared__ double e[NUM_TTA];
    __shared__ int    sv[NUM_TTA];
    __shared__ float  counts[N_COLS];

    const int b = blockIdx.x;
    const int t = threadIdx.x;

    e[t] = ent[b * NUM_TTA + t];
    const int myv = votes[b * NUM_TTA + t];
    for (int c = t; c < N_COLS; c += NUM_TTA) counts[c] = 0.f;
    __syncthreads();

    const double et = e[t];
    int rank = 0;
#pragma unroll
    for (int i = 0; i < NUM_TTA; ++i) {
        const double ei = e[i];
        rank += (ei < et) || (ei == et && i < t);
    }
    sv[rank] = myv;
    __syncthreads();

    if (t == 0) {
        for (int j = 0; j < KEPT; ++j) counts[sv[j]] += 1.f;
        float Mv = 0.f; int Tc = 0;
        for (int j = 0; j < KEPT; ++j) {
            const int c = sv[j];
            bool dup = false;
            for (int q = 0; q < j; ++q) dup = dup || (sv[q] == c);
            if (dup) continue;
            const float cv = counts[c];
            if (cv > Mv) { Mv = cv; Tc = 1; }
            else if (cv == Mv) { Tc += 1; }
        }
        for (int i = 0; i < NUM_TTA - KEPT; ++i) {
            if (Tc <= 1) break;
            const int c = sv[KEPT + i];
            const float oldc = counts[c];
            counts[c] = oldc + 1.f;
            if (oldc == Mv)            { Mv += 1.f; Tc = 1; }
            else if (oldc + 1.f == Mv) { Tc += 1; }
        }
    }
    __syncthreads();

    const size_t o0 = (size_t)b * N_COLS;
    for (int c = t; c < N_COLS; c += NUM_TTA)
        out[o0 + c] = logf(counts[c] * (1.f / 64.f) + 1e-8f);
}

// -------------------------------- launch --------------------------------
extern "C" void kernel_launch(void* const* d_in, const int* in_sizes, int n_in,
                              void* d_out, int out_size, void* d_ws, size_t ws_size,
                              hipStream_t stream) {
    const float* x    = (const float*)d_in[0];
    const float* Wm   = (const float*)d_in[1];
    const float* bias = (const float*)d_in[2];
    float* out = (float*)d_out;

    // ws layout: ent f64[16384] | votes i32[16384] | Wh,Wl bf16[1024*4096]
    //            | per-chunk logits f32[R*1000]   (A split fused in GEMM)
    char* p = (char*)d_ws;
    double* ent  = (double*)p;                     p += (size_t)M_ROWS * 8;
    int*   votes = (int*)p;                        p += (size_t)M_ROWS * 4;
    unsigned short* Wh = (unsigned short*)p;       p += (size_t)N_PAD * K_DIM * 2;
    unsigned short* Wl = (unsigned short*)p;       p += (size_t)N_PAD * K_DIM * 2;
    const size_t base = (size_t)(p - (char*)d_ws);

    // R: rows per chunk, multiple of 2048 so m_tiles (rows/256) is divisible by 8
    long long R = 0;
    if (ws_size > base) R = (long long)((ws_size - base) / (size_t)4000);
    R = (R / 2048) * 2048;
    if (R > CHUNK_MAX) R = CHUNK_MAX;
    if (R < 2048) R = 2048;

    float* logits = (float*)p;

    split_w<<<dim3(K_DIM / 32, N_PAD / 32), dim3(32, 32), 0, stream>>>(Wm, Wh, Wl);

    for (int m0 = 0; m0 < M_ROWS; m0 += (int)R) {
        const int rows = (int)(((long long)(M_ROWS - m0) < R) ? (M_ROWS - m0) : R);
        const int m_tiles = rows / 256;
        gemm_mfma<<<4 * m_tiles, 512, 0, stream>>>(
            x + (size_t)m0 * K_DIM, Wh, Wl, bias, logits, m_tiles);
        row_stats<<<rows / 4, 256, 0, stream>>>(logits, ent, votes, m0);
    }
    vote_kernel<<<BATCH, NUM_TTA, 0, stream>>>(ent, votes, out);
}

// Round 10
// 657.509 us; speedup vs baseline: 1.0422x; 1.0338x over previous
//
#include <hip/hip_runtime.h>
#include <cstdint>
#include <cstddef>
#include <math.h>

#define M_ROWS 16384
#define N_COLS 1000
#define N_PAD  1024
#define K_DIM  4096
#define NUM_TTA 64
#define KEPT 6
#define BATCH 256
#define NKT (K_DIM / 32)       // 128 K-tiles of 32

typedef __attribute__((ext_vector_type(8))) short short8;
typedef __attribute__((ext_vector_type(4))) float v4f;

#define GL_LDS16(g, l)                                                        \
    __builtin_amdgcn_global_load_lds(                                         \
        (const __attribute__((address_space(1))) unsigned int*)(g),           \
        (__attribute__((address_space(3))) unsigned int*)(l), 16, 0, 0)

// ---- RNE bf16 split via HW cvt: x = hi + lo (+ ~2^-18 rel) ----
__device__ __forceinline__ void split2(float x, unsigned short& h, unsigned short& l) {
    const __bf16 hb = (__bf16)x;
    const float hf  = (float)hb;
    const __bf16 lb = (__bf16)(x - hf);
    h = __builtin_bit_cast(unsigned short, hb);
    l = __builtin_bit_cast(unsigned short, lb);
}

// 8 floats -> 8 hi bf16 + 8 lo bf16
__device__ __forceinline__ void split8(const float4& a, const float4& b,
                                       short8& hv, short8& lv) {
    unsigned short h, l;
    split2(a.x, h, l); hv[0] = (short)h; lv[0] = (short)l;
    split2(a.y, h, l); hv[1] = (short)h; lv[1] = (short)l;
    split2(a.z, h, l); hv[2] = (short)h; lv[2] = (short)l;
    split2(a.w, h, l); hv[3] = (short)h; lv[3] = (short)l;
    split2(b.x, h, l); hv[4] = (short)h; lv[4] = (short)l;
    split2(b.y, h, l); hv[5] = (short)h; lv[5] = (short)l;
    split2(b.z, h, l); hv[6] = (short)h; lv[6] = (short)l;
    split2(b.w, h, l); hv[7] = (short)h; lv[7] = (short)l;
}

// ---- inline f64 exp for d <= 0: rndne + 2-part ln2 + degree-12 Horner ----
__device__ __forceinline__ double exp_neg(double d) {
    if (d < -700.0) return 0.0;
    const double kd = rint(d * 1.4426950408889634074);
    double r = fma(-kd, 6.93147180369123816490e-01, d);
    r = fma(-kd, 1.90821492927058770002e-10, r);
    double p = 2.08767569878680989792e-09;      // 1/12!
    p = fma(p, r, 2.50521083854417187751e-08);  // 1/11!
    p = fma(p, r, 2.75573192239858906526e-07);  // 1/10!
    p = fma(p, r, 2.75573192239858925110e-06);  // 1/9!
    p = fma(p, r, 2.48015873015873015873e-05);  // 1/8!
    p = fma(p, r, 1.98412698412698412526e-04);  // 1/7!
    p = fma(p, r, 1.38888888888888894069e-03);  // 1/6!
    p = fma(p, r, 8.33333333333333321769e-03);  // 1/5!
    p = fma(p, r, 4.16666666666666643537e-02);  // 1/4!
    p = fma(p, r, 1.66666666666666657415e-01);  // 1/3!
    p = fma(p, r, 5.0e-01);
    p = fma(p, r, 1.0);
    p = fma(p, r, 1.0);
    const long long k = (long long)kd;
    return p * __longlong_as_double((1023LL + k) << 52);
}

// ---------------- W: transpose 4096x1000 -> [n][k] 1024x4096, split ----------------
__global__ __launch_bounds__(1024)
void split_w(const float* __restrict__ W, unsigned short* __restrict__ Wh,
             unsigned short* __restrict__ Wl)
{
    __shared__ float tile[32][33];
    const int k0 = blockIdx.x * 32, n0 = blockIdx.y * 32;
    const int tx = threadIdx.x, ty = threadIdx.y;
    const int n = n0 + tx, k = k0 + ty;
    tile[ty][tx] = (n < N_COLS) ? W[(size_t)k * N_COLS + n] : 0.f;
    __syncthreads();
    const float w = tile[tx][ty];           // = W[k0+tx][n0+ty]
    unsigned short h, l;
    split2(w, h, l);
    const size_t o = (size_t)(n0 + ty) * K_DIM + k0 + tx;
    Wh[o] = h; Wl[o] = l;
}

// ------------- GEMM + fused partial softmax stats -------------
// 256x256 tile, 512 thr = 8 waves (2m x 4n), wave = 128x64 out, BK=32,
// 16x16x32 MFMA, r7's fenced read/MFMA K-loop (measured best, 363us).
// Round-10 change: NO logits write.  Epilogue computes per-(row, 64-col
// chunk) online-softmax partials {S, T, m, argmax} in-register (shfl
// reductions within 16-lane half-groups) and writes 8 MB of partials;
// vote_kernel merges the 16 chunks per row deterministically.
__global__ __launch_bounds__(512, 2)
void gemm_mfma(const float* __restrict__ X,
               const unsigned short* __restrict__ Bh_, const unsigned short* __restrict__ Bl_,
               const float* __restrict__ bias, double* __restrict__ part,
               int m_tiles)
{
    __shared__ __attribute__((aligned(16))) char smem[2 * 4 * 16384];

    const int t    = threadIdx.x;
    const int lane = t & 63;
    const int wave = t >> 6;
    const int wr   = wave >> 2;        // 0..1  m-half of block tile
    const int wc   = wave & 3;         // 0..3  n-quarter
    const int ml   = lane & 15;
    const int kh   = lane >> 4;        // k-slot (8 bf16 each)

    // ---- XCD swizzle ----
    const int bid  = blockIdx.x;
    const int xcd  = bid & 7;
    const int slot = bid >> 3;
    const int mt   = xcd * (m_tiles >> 3) + (slot >> 2);
    const int nt   = slot & 3;
    const int m0 = mt * 256, n0 = nt * 256;

    // ---- B staging (global_load_lds, pre-swizzled source) ----
    const int    schunk = (t & 3) ^ ((t >> 3) & 3);
    const size_t ro     = (size_t)(t >> 2) * (K_DIM * 2) + (size_t)schunk * 16;
    const char* gBh = (const char*)Bh_ + (size_t)n0 * (K_DIM * 2) + ro;
    const char* gBl = (const char*)Bl_ + (size_t)n0 * (K_DIM * 2) + ro;
    char* ldst = smem + t * 16;
    const size_t RSTEP = (size_t)128 * K_DIM * 2;   // +128 rows

    // ---- A staging (reg path): thread t covers row ar, 16-float half ahalf ----
    const int ar    = t >> 1;          // 0..255
    const int ahalf = t & 1;           // k 0-15 or 16-31 within tile
    const float* gA = X + (size_t)(m0 + ar) * K_DIM + ahalf * 16;
    const int sig = (ar >> 1) & 3;     // row swizzle key (matches reader)
    const int s0  = (ahalf * 2) ^ sig;
    const int s1  = (ahalf * 2 + 1) ^ sig;
    const int aw0 = ar * 64 + (s0 << 4);   // LDS byte off in A panel, floats 0-7
    const int aw1 = ar * 64 + (s1 << 4);   // floats 8-15

    // ---- per-lane LDS read bases (bytes within one 16KB mat panel) ----
    const int swz = ((kh ^ (ml >> 1)) & 3) << 4;
    const int lbA = wr * 8192 + ml * 64 + swz;
    const int lbB = wc * 4096 + ml * 64 + swz;

    v4f acc[8][4];
#pragma unroll
    for (int i = 0; i < 8; ++i)
#pragma unroll
        for (int j = 0; j < 4; ++j) acc[i][j] = (v4f){0.f, 0.f, 0.f, 0.f};

#define FRAG(P) (*(const short8*)(smem + (P)))
#define SB __builtin_amdgcn_sched_barrier(0)

    short8 ah[4], al[4], bh[4], bl[4];

    // ---------------- prologue: stage K-tile 0 into buf 0 ----------------
    {
        const float4 fa = *(const float4*)(gA);
        const float4 fb = *(const float4*)(gA + 4);
        const float4 fc = *(const float4*)(gA + 8);
        const float4 fd = *(const float4*)(gA + 12);
        GL_LDS16(gBh,         ldst + 32768);
        GL_LDS16(gBh + RSTEP, ldst + 40960);
        GL_LDS16(gBl,         ldst + 49152);
        GL_LDS16(gBl + RSTEP, ldst + 57344);
        short8 hv, lv;
        split8(fa, fb, hv, lv);
        *(short8*)(smem + aw0) = hv;
        *(short8*)(smem + 16384 + aw0) = lv;
        split8(fc, fd, hv, lv);
        *(short8*)(smem + aw1) = hv;
        *(short8*)(smem + 16384 + aw1) = lv;
    }
    __syncthreads();

#define RD_B(NF) do {                                                         \
    bh[NF] = FRAG(B0 + 32768 + (NF) * 1024 + lbB);                            \
    bl[NF] = FRAG(B0 + 49152 + (NF) * 1024 + lbB);                            \
} while (0)
#define RD_A(MF, HO) do {                                                     \
    ah[MF] = FRAG(B0 + (HO) +         (MF) * 1024 + lbA);                     \
    al[MF] = FRAG(B0 + (HO) + 16384 + (MF) * 1024 + lbA);                     \
} while (0)
#define MCLN(NF) do {                                                         \
    __builtin_amdgcn_s_setprio(1);                                            \
    _Pragma("unroll")                                                         \
    for (int mf = 0; mf < 4; ++mf)                                            \
        acc[mf][NF] = __builtin_amdgcn_mfma_f32_16x16x32_bf16(ah[mf], bl[NF], acc[mf][NF], 0, 0, 0); \
    _Pragma("unroll")                                                         \
    for (int mf = 0; mf < 4; ++mf)                                            \
        acc[mf][NF] = __builtin_amdgcn_mfma_f32_16x16x32_bf16(al[mf], bh[NF], acc[mf][NF], 0, 0, 0); \
    _Pragma("unroll")                                                         \
    for (int mf = 0; mf < 4; ++mf)                                            \
        acc[mf][NF] = __builtin_amdgcn_mfma_f32_16x16x32_bf16(ah[mf], bh[NF], acc[mf][NF], 0, 0, 0); \
    __builtin_amdgcn_s_setprio(0);                                            \
} while (0)
#define MCLM(MF) do {                                                         \
    __builtin_amdgcn_s_setprio(1);                                            \
    _Pragma("unroll")                                                         \
    for (int nf = 0; nf < 4; ++nf)                                            \
        acc[4 + (MF)][nf] = __builtin_amdgcn_mfma_f32_16x16x32_bf16(ah[MF], bl[nf], acc[4 + (MF)][nf], 0, 0, 0); \
    _Pragma("unroll")                                                         \
    for (int nf = 0; nf < 4; ++nf)                                            \
        acc[4 + (MF)][nf] = __builtin_amdgcn_mfma_f32_16x16x32_bf16(al[MF], bh[nf], acc[4 + (MF)][nf], 0, 0, 0); \
    _Pragma("unroll")                                                         \
    for (int nf = 0; nf < 4; ++nf)                                            \
        acc[4 + (MF)][nf] = __builtin_amdgcn_mfma_f32_16x16x32_bf16(ah[MF], bh[nf], acc[4 + (MF)][nf], 0, 0, 0); \
    __builtin_amdgcn_s_setprio(0);                                            \
} while (0)

#define TILE_BODY(KT, RB) do {                                                \
    const int B0 = (RB) * 65536;                                              \
    const int B1 = ((RB) ^ 1) * 65536;                                        \
    asm volatile("s_waitcnt vmcnt(0) lgkmcnt(0)" ::: "memory");               \
    __builtin_amdgcn_s_barrier();                                             \
    SB;                                                                       \
    const bool pf = (KT) + 1 < NKT;                                           \
    float4 fa, fb;                                                            \
    if (pf) {                                                                 \
        const float* ga_ = gA + ((KT) + 1) * 32;                              \
        fa = *(const float4*)(ga_);                                           \
        fb = *(const float4*)(ga_ + 4);                                       \
        const int kb_ = ((KT) + 1) * 64;                                      \
        GL_LDS16(gBh + kb_,         ldst + B1 + 32768);                       \
        GL_LDS16(gBh + RSTEP + kb_, ldst + B1 + 40960);                       \
        GL_LDS16(gBl + kb_,         ldst + B1 + 49152);                       \
        GL_LDS16(gBl + RSTEP + kb_, ldst + B1 + 57344);                       \
    }                                                                         \
    RD_B(0);                                                                  \
    RD_A(0, 0); RD_A(1, 0); RD_A(2, 0); RD_A(3, 0);                           \
    RD_B(1);                                                                  \
    SB;                                                                       \
    MCLN(0); SB;                                                              \
    RD_B(2); SB;                                                              \
    MCLN(1); SB;                                                              \
    RD_B(3); SB;                                                              \
    MCLN(2); SB;                                                              \
    MCLN(3); SB;                                                              \
    RD_A(0, 4096); RD_A(1, 4096); SB;                                         \
    MCLM(0); SB;                                                              \
    if (pf) {                                                                 \
        short8 hv, lv;                                                        \
        split8(fa, fb, hv, lv);                                               \
        *(short8*)(smem + B1 + aw0) = hv;                                     \
        *(short8*)(smem + B1 + 16384 + aw0) = lv;                             \
        const float* ga_ = gA + ((KT) + 1) * 32 + 8;                          \
        fa = *(const float4*)(ga_);                                           \
        fb = *(const float4*)(ga_ + 4);                                       \
    }                                                                         \
    SB;                                                                       \
    RD_A(2, 4096); SB;                                                        \
    MCLM(1); SB;                                                              \
    RD_A(3, 4096); SB;                                                        \
    MCLM(2); SB;                                                              \
    if (pf) {                                                                 \
        short8 hv, lv;                                                        \
        split8(fa, fb, hv, lv);                                               \
        *(short8*)(smem + B1 + aw1) = hv;                                     \
        *(short8*)(smem + B1 + 16384 + aw1) = lv;                             \
    }                                                                         \
    SB;                                                                       \
    MCLM(3);                                                                  \
} while (0)

#pragma unroll 1
    for (int kt = 0; kt < NKT; kt += 2) {
        TILE_BODY(kt, 0);
        TILE_BODY(kt + 1, 1);
    }

    // ---- fused epilogue: per-(row, chunk) online-softmax partials ----
    // C/D layout: col = lane&15 (ml), row = kh*4 + reg  [m89/m91].
    // chunk = nt*4 + wc covers cols chunk*64 .. +63; row stats reduced
    // across the 16-lane half-group (shfl_xor 8,4,2,1 stays in group).
    const int chunk = nt * 4 + wc;
    const int colbase = n0 + wc * 64;
    float bcol[4]; bool bval[4];
#pragma unroll
    for (int ni = 0; ni < 4; ++ni) {
        const int col = colbase + ni * 16 + ml;
        bval[ni] = (col < N_COLS);
        bcol[ni] = bval[ni] ? bias[col] : 0.f;
    }
#pragma unroll
    for (int mi = 0; mi < 8; ++mi) {
        const int rbase = m0 + wr * 128 + (mi >> 2) * 64 + (mi & 3) * 16 + kh * 4;
#pragma unroll
        for (int r = 0; r < 4; ++r) {
            float x[4];
            float bv = -3.0e38f; int bi = 0;
#pragma unroll
            for (int ni = 0; ni < 4; ++ni) {
                x[ni] = acc[mi][ni][r] + bcol[ni];
                const int col = colbase + ni * 16 + ml;
                if (bval[ni] && x[ni] > bv) { bv = x[ni]; bi = col; }
            }
#pragma unroll
            for (int s = 8; s > 0; s >>= 1) {
                const float ov = __shfl_xor(bv, s);
                const int   oi = __shfl_xor(bi, s);
                if (ov > bv || (ov == bv && oi < bi)) { bv = ov; bi = oi; }
            }
            double S = 0.0, T = 0.0;
#pragma unroll
            for (int ni = 0; ni < 4; ++ni) {
                if (bval[ni]) {
                    const float d = x[ni] - bv;
                    const double e = exp_neg((double)d);
                    S += e; T += e * (double)d;
                }
            }
#pragma unroll
            for (int s = 8; s > 0; s >>= 1) {
                S += __shfl_xor(S, s);
                T += __shfl_xor(T, s);
            }
            if (ml == 0) {
                double* pp = part + ((size_t)(rbase + r) * 16 + chunk) * 4;
                pp[0] = S; pp[1] = T; pp[2] = (double)bv; pp[3] = (double)bi;
            }
        }
    }
#undef TILE_BODY
#undef MCLM
#undef MCLN
#undef RD_A
#undef RD_B
#undef SB
#undef FRAG
}

// ------------- per-batch: merge partials, stable sort by entropy, tie loop -------------
__global__ __launch_bounds__(64)
void vote_kernel(const double* __restrict__ part, float* __restrict__ out)
{
    __shared__ double e[NUM_TTA];
    __shared__ int    sv[NUM_TTA];
    __shared__ float  counts[N_COLS];

    const int b = blockIdx.x;
    const int t = threadIdx.x;
    const int row = b * NUM_TTA + t;

    // ---- merge 16 chunk partials (ascending chunk = ascending cols) ----
    const double* pp = part + (size_t)row * 64;
    float m = -3.0e38f; int amax = 0;
#pragma unroll
    for (int c = 0; c < 16; ++c) {
        const float pm = (float)pp[c * 4 + 2];
        const int   pa = (int)pp[c * 4 + 3];
        if (pm > m) { m = pm; amax = pa; }   // strict > : earlier chunk (lower col) wins ties
    }
    double S = 0.0, T = 0.0;
#pragma unroll
    for (int c = 0; c < 16; ++c) {
        const double dm = (double)((float)pp[c * 4 + 2]) - (double)m;
        const double f  = exp_neg(dm);
        S += pp[c * 4 + 0] * f;
        T += (pp[c * 4 + 1] + dm * pp[c * 4 + 0]) * f;
    }
    e[t] = log(S) - T / S;
    const int myv = amax;
    for (int c = t; c < N_COLS; c += NUM_TTA) counts[c] = 0.f;
    __syncthreads();

    const double et = e[t];
    int rank = 0;
#pragma unroll
    for (int i = 0; i < NUM_TTA; ++i) {
        const double ei = e[i];
        rank += (ei < et) || (ei == et && i < t);
    }
    sv[rank] = myv;
    __syncthreads();

    if (t == 0) {
        for (int j = 0; j < KEPT; ++j) counts[sv[j]] += 1.f;
        float Mv = 0.f; int Tc = 0;
        for (int j = 0; j < KEPT; ++j) {
            const int c = sv[j];
            bool dup = false;
            for (int q = 0; q < j; ++q) dup = dup || (sv[q] == c);
            if (dup) continue;
            const float cv = counts[c];
            if (cv > Mv) { Mv = cv; Tc = 1; }
            else if (cv == Mv) { Tc += 1; }
        }
        for (int i = 0; i < NUM_TTA - KEPT; ++i) {
            if (Tc <= 1) break;
            const int c = sv[KEPT + i];
            const float oldc = counts[c];
            counts[c] = oldc + 1.f;
            if (oldc == Mv)            { Mv += 1.f; Tc = 1; }
            else if (oldc + 1.f == Mv) { Tc += 1; }
        }
    }
    __syncthreads();

    const size_t o0 = (size_t)b * N_COLS;
    for (int c = t; c < N_COLS; c += NUM_TTA)
        out[o0 + c] = logf(counts[c] * (1.f / 64.f) + 1e-8f);
}

// -------------------------------- launch --------------------------------
extern "C" void kernel_launch(void* const* d_in, const int* in_sizes, int n_in,
                              void* d_out, int out_size, void* d_ws, size_t ws_size,
                              hipStream_t stream) {
    const float* x    = (const float*)d_in[0];
    const float* Wm   = (const float*)d_in[1];
    const float* bias = (const float*)d_in[2];
    float* out = (float*)d_out;

    // ws layout: part f64[16384*16*4] (8 MB) | Wh,Wl bf16[1024*4096]
    char* p = (char*)d_ws;
    double* part = (double*)p;                     p += (size_t)M_ROWS * 16 * 4 * 8;
    unsigned short* Wh = (unsigned short*)p;       p += (size_t)N_PAD * K_DIM * 2;
    unsigned short* Wl = (unsigned short*)p;       p += (size_t)N_PAD * K_DIM * 2;

    split_w<<<dim3(K_DIM / 32, N_PAD / 32), dim3(32, 32), 0, stream>>>(Wm, Wh, Wl);

    const int m_tiles = M_ROWS / 256;   // 64, divisible by 8
    gemm_mfma<<<4 * m_tiles, 512, 0, stream>>>(
        x, Wh, Wl, bias, part, m_tiles);
    vote_kernel<<<BATCH, NUM_TTA, 0, stream>>>(part, out);
}

// Round 11
// 639.807 us; speedup vs baseline: 1.0710x; 1.0277x over previous
//
#include <hip/hip_runtime.h>
#include <cstdint>
#include <cstddef>
#include <math.h>

#define M_ROWS 16384
#define N_COLS 1000
#define N_PAD  1024
#define K_DIM  4096
#define NUM_TTA 64
#define KEPT 6
#define BATCH 256
#define NKT (K_DIM / 32)       // 128 K-tiles of 32

typedef __attribute__((ext_vector_type(8))) short short8;
typedef __attribute__((ext_vector_type(4))) float v4f;

#define GL_LDS16(g, l)                                                        \
    __builtin_amdgcn_global_load_lds(                                         \
        (const __attribute__((address_space(1))) unsigned int*)(g),           \
        (__attribute__((address_space(3))) unsigned int*)(l), 16, 0, 0)

// ---- RNE bf16 split via HW cvt: x = hi + lo (+ ~2^-18 rel) ----
__device__ __forceinline__ void split2(float x, unsigned short& h, unsigned short& l) {
    const __bf16 hb = (__bf16)x;
    const float hf  = (float)hb;
    const __bf16 lb = (__bf16)(x - hf);
    h = __builtin_bit_cast(unsigned short, hb);
    l = __builtin_bit_cast(unsigned short, lb);
}

// 8 floats -> 8 hi bf16 + 8 lo bf16
__device__ __forceinline__ void split8(const float4& a, const float4& b,
                                       short8& hv, short8& lv) {
    unsigned short h, l;
    split2(a.x, h, l); hv[0] = (short)h; lv[0] = (short)l;
    split2(a.y, h, l); hv[1] = (short)h; lv[1] = (short)l;
    split2(a.z, h, l); hv[2] = (short)h; lv[2] = (short)l;
    split2(a.w, h, l); hv[3] = (short)h; lv[3] = (short)l;
    split2(b.x, h, l); hv[4] = (short)h; lv[4] = (short)l;
    split2(b.y, h, l); hv[5] = (short)h; lv[5] = (short)l;
    split2(b.z, h, l); hv[6] = (short)h; lv[6] = (short)l;
    split2(b.w, h, l); hv[7] = (short)h; lv[7] = (short)l;
}

// ---- inline f64 exp for d <= 0 (vote-side merge only; 16 calls/thread) ----
__device__ __forceinline__ double exp_neg(double d) {
    if (d < -700.0) return 0.0;
    const double kd = rint(d * 1.4426950408889634074);
    double r = fma(-kd, 6.93147180369123816490e-01, d);
    r = fma(-kd, 1.90821492927058770002e-10, r);
    double p = 2.08767569878680989792e-09;      // 1/12!
    p = fma(p, r, 2.50521083854417187751e-08);  // 1/11!
    p = fma(p, r, 2.75573192239858906526e-07);  // 1/10!
    p = fma(p, r, 2.75573192239858925110e-06);  // 1/9!
    p = fma(p, r, 2.48015873015873015873e-05);  // 1/8!
    p = fma(p, r, 1.98412698412698412526e-04);  // 1/7!
    p = fma(p, r, 1.38888888888888894069e-03);  // 1/6!
    p = fma(p, r, 8.33333333333333321769e-03);  // 1/5!
    p = fma(p, r, 4.16666666666666643537e-02);  // 1/4!
    p = fma(p, r, 1.66666666666666657415e-01);  // 1/3!
    p = fma(p, r, 5.0e-01);
    p = fma(p, r, 1.0);
    p = fma(p, r, 1.0);
    const long long k = (long long)kd;
    return p * __longlong_as_double((1023LL + k) << 52);
}

// ---------------- W: transpose 4096x1000 -> [n][k] 1024x4096, split ----------------
__global__ __launch_bounds__(1024)
void split_w(const float* __restrict__ W, unsigned short* __restrict__ Wh,
             unsigned short* __restrict__ Wl)
{
    __shared__ float tile[32][33];
    const int k0 = blockIdx.x * 32, n0 = blockIdx.y * 32;
    const int tx = threadIdx.x, ty = threadIdx.y;
    const int n = n0 + tx, k = k0 + ty;
    tile[ty][tx] = (n < N_COLS) ? W[(size_t)k * N_COLS + n] : 0.f;
    __syncthreads();
    const float w = tile[tx][ty];           // = W[k0+tx][n0+ty]
    unsigned short h, l;
    split2(w, h, l);
    const size_t o = (size_t)(n0 + ty) * K_DIM + k0 + tx;
    Wh[o] = h; Wl[o] = l;
}

// ------------- GEMM + fused partial softmax stats -------------
// 256x256 tile, 512 thr = 8 waves (2m x 4n), wave = 128x64 out, BK=32,
// 16x16x32 MFMA, r7's fenced read/MFMA K-loop (measured best).
// Round-11 change: epilogue exp in f32 HW (v_exp_f32) with f64 accumulation.
// Precision: reference entropy is f32 (~1e-5.5 abs err) and our f64 path
// matched it exactly (absmax=0) -> ordering gaps >> 1e-5.5; f32-exp error
// (~1e-7) is 100x below the demonstrated tolerance.
__global__ __launch_bounds__(512, 2)
void gemm_mfma(const float* __restrict__ X,
               const unsigned short* __restrict__ Bh_, const unsigned short* __restrict__ Bl_,
               const float* __restrict__ bias, double* __restrict__ part,
               int m_tiles)
{
    __shared__ __attribute__((aligned(16))) char smem[2 * 4 * 16384];

    const int t    = threadIdx.x;
    const int lane = t & 63;
    const int wave = t >> 6;
    const int wr   = wave >> 2;        // 0..1  m-half of block tile
    const int wc   = wave & 3;         // 0..3  n-quarter
    const int ml   = lane & 15;
    const int kh   = lane >> 4;        // k-slot (8 bf16 each)

    // ---- XCD swizzle ----
    const int bid  = blockIdx.x;
    const int xcd  = bid & 7;
    const int slot = bid >> 3;
    const int mt   = xcd * (m_tiles >> 3) + (slot >> 2);
    const int nt   = slot & 3;
    const int m0 = mt * 256, n0 = nt * 256;

    // ---- B staging (global_load_lds, pre-swizzled source) ----
    const int    schunk = (t & 3) ^ ((t >> 3) & 3);
    const size_t ro     = (size_t)(t >> 2) * (K_DIM * 2) + (size_t)schunk * 16;
    const char* gBh = (const char*)Bh_ + (size_t)n0 * (K_DIM * 2) + ro;
    const char* gBl = (const char*)Bl_ + (size_t)n0 * (K_DIM * 2) + ro;
    char* ldst = smem + t * 16;
    const size_t RSTEP = (size_t)128 * K_DIM * 2;   // +128 rows

    // ---- A staging (reg path): thread t covers row ar, 16-float half ahalf ----
    const int ar    = t >> 1;          // 0..255
    const int ahalf = t & 1;           // k 0-15 or 16-31 within tile
    const float* gA = X + (size_t)(m0 + ar) * K_DIM + ahalf * 16;
    const int sig = (ar >> 1) & 3;     // row swizzle key (matches reader)
    const int s0  = (ahalf * 2) ^ sig;
    const int s1  = (ahalf * 2 + 1) ^ sig;
    const int aw0 = ar * 64 + (s0 << 4);   // LDS byte off in A panel, floats 0-7
    const int aw1 = ar * 64 + (s1 << 4);   // floats 8-15

    // ---- per-lane LDS read bases (bytes within one 16KB mat panel) ----
    const int swz = ((kh ^ (ml >> 1)) & 3) << 4;
    const int lbA = wr * 8192 + ml * 64 + swz;
    const int lbB = wc * 4096 + ml * 64 + swz;

    v4f acc[8][4];
#pragma unroll
    for (int i = 0; i < 8; ++i)
#pragma unroll
        for (int j = 0; j < 4; ++j) acc[i][j] = (v4f){0.f, 0.f, 0.f, 0.f};

#define FRAG(P) (*(const short8*)(smem + (P)))
#define SB __builtin_amdgcn_sched_barrier(0)

    short8 ah[4], al[4], bh[4], bl[4];

    // ---------------- prologue: stage K-tile 0 into buf 0 ----------------
    {
        const float4 fa = *(const float4*)(gA);
        const float4 fb = *(const float4*)(gA + 4);
        const float4 fc = *(const float4*)(gA + 8);
        const float4 fd = *(const float4*)(gA + 12);
        GL_LDS16(gBh,         ldst + 32768);
        GL_LDS16(gBh + RSTEP, ldst + 40960);
        GL_LDS16(gBl,         ldst + 49152);
        GL_LDS16(gBl + RSTEP, ldst + 57344);
        short8 hv, lv;
        split8(fa, fb, hv, lv);
        *(short8*)(smem + aw0) = hv;
        *(short8*)(smem + 16384 + aw0) = lv;
        split8(fc, fd, hv, lv);
        *(short8*)(smem + aw1) = hv;
        *(short8*)(smem + 16384 + aw1) = lv;
    }
    __syncthreads();

#define RD_B(NF) do {                                                         \
    bh[NF] = FRAG(B0 + 32768 + (NF) * 1024 + lbB);                            \
    bl[NF] = FRAG(B0 + 49152 + (NF) * 1024 + lbB);                            \
} while (0)
#define RD_A(MF, HO) do {                                                     \
    ah[MF] = FRAG(B0 + (HO) +         (MF) * 1024 + lbA);                     \
    al[MF] = FRAG(B0 + (HO) + 16384 + (MF) * 1024 + lbA);                     \
} while (0)
#define MCLN(NF) do {                                                         \
    __builtin_amdgcn_s_setprio(1);                                            \
    _Pragma("unroll")                                                         \
    for (int mf = 0; mf < 4; ++mf)                                            \
        acc[mf][NF] = __builtin_amdgcn_mfma_f32_16x16x32_bf16(ah[mf], bl[NF], acc[mf][NF], 0, 0, 0); \
    _Pragma("unroll")                                                         \
    for (int mf = 0; mf < 4; ++mf)                                            \
        acc[mf][NF] = __builtin_amdgcn_mfma_f32_16x16x32_bf16(al[mf], bh[NF], acc[mf][NF], 0, 0, 0); \
    _Pragma("unroll")                                                         \
    for (int mf = 0; mf < 4; ++mf)                                            \
        acc[mf][NF] = __builtin_amdgcn_mfma_f32_16x16x32_bf16(ah[mf], bh[NF], acc[mf][NF], 0, 0, 0); \
    __builtin_amdgcn_s_setprio(0);                                            \
} while (0)
#define MCLM(MF) do {                                                         \
    __builtin_amdgcn_s_setprio(1);                                            \
    _Pragma("unroll")                                                         \
    for (int nf = 0; nf < 4; ++nf)                                            \
        acc[4 + (MF)][nf] = __builtin_amdgcn_mfma_f32_16x16x32_bf16(ah[MF], bl[nf], acc[4 + (MF)][nf], 0, 0, 0); \
    _Pragma("unroll")                                                         \
    for (int nf = 0; nf < 4; ++nf)                                            \
        acc[4 + (MF)][nf] = __builtin_amdgcn_mfma_f32_16x16x32_bf16(al[MF], bh[nf], acc[4 + (MF)][nf], 0, 0, 0); \
    _Pragma("unroll")                                                         \
    for (int nf = 0; nf < 4; ++nf)                                            \
        acc[4 + (MF)][nf] = __builtin_amdgcn_mfma_f32_16x16x32_bf16(ah[MF], bh[nf], acc[4 + (MF)][nf], 0, 0, 0); \
    __builtin_amdgcn_s_setprio(0);                                            \
} while (0)

#define TILE_BODY(KT, RB) do {                                                \
    const int B0 = (RB) * 65536;                                              \
    const int B1 = ((RB) ^ 1) * 65536;                                        \
    asm volatile("s_waitcnt vmcnt(0) lgkmcnt(0)" ::: "memory");               \
    __builtin_amdgcn_s_barrier();                                             \
    SB;                                                                       \
    const bool pf = (KT) + 1 < NKT;                                           \
    float4 fa, fb;                                                            \
    if (pf) {                                                                 \
        const float* ga_ = gA + ((KT) + 1) * 32;                              \
        fa = *(const float4*)(ga_);                                           \
        fb = *(const float4*)(ga_ + 4);                                       \
        const int kb_ = ((KT) + 1) * 64;                                      \
        GL_LDS16(gBh + kb_,         ldst + B1 + 32768);                       \
        GL_LDS16(gBh + RSTEP + kb_, ldst + B1 + 40960);                       \
        GL_LDS16(gBl + kb_,         ldst + B1 + 49152);                       \
        GL_LDS16(gBl + RSTEP + kb_, ldst + B1 + 57344);                       \
    }                                                                         \
    RD_B(0);                                                                  \
    RD_A(0, 0); RD_A(1, 0); RD_A(2, 0); RD_A(3, 0);                           \
    RD_B(1);                                                                  \
    SB;                                                                       \
    MCLN(0); SB;                                                              \
    RD_B(2); SB;                                                              \
    MCLN(1); SB;                                                              \
    RD_B(3); SB;                                                              \
    MCLN(2); SB;                                                              \
    MCLN(3); SB;                                                              \
    RD_A(0, 4096); RD_A(1, 4096); SB;                                         \
    MCLM(0); SB;                                                              \
    if (pf) {                                                                 \
        short8 hv, lv;                                                        \
        split8(fa, fb, hv, lv);                                               \
        *(short8*)(smem + B1 + aw0) = hv;                                     \
        *(short8*)(smem + B1 + 16384 + aw0) = lv;                             \
        const float* ga_ = gA + ((KT) + 1) * 32 + 8;                          \
        fa = *(const float4*)(ga_);                                           \
        fb = *(const float4*)(ga_ + 4);                                       \
    }                                                                         \
    SB;                                                                       \
    RD_A(2, 4096); SB;                                                        \
    MCLM(1); SB;                                                              \
    RD_A(3, 4096); SB;                                                        \
    MCLM(2); SB;                                                              \
    if (pf) {                                                                 \
        short8 hv, lv;                                                        \
        split8(fa, fb, hv, lv);                                               \
        *(short8*)(smem + B1 + aw1) = hv;                                     \
        *(short8*)(smem + B1 + 16384 + aw1) = lv;                             \
    }                                                                         \
    SB;                                                                       \
    MCLM(3);                                                                  \
} while (0)

#pragma unroll 1
    for (int kt = 0; kt < NKT; kt += 2) {
        TILE_BODY(kt, 0);
        TILE_BODY(kt + 1, 1);
    }

    // ---- fused epilogue: per-(row, chunk) online-softmax partials ----
    // C/D layout: col = lane&15 (ml), row = kh*4 + reg  [m89/m91].
    // chunk = nt*4 + wc covers cols chunk*64 .. +63; stats reduced across
    // the 16-lane half-group (shfl_xor 8,4,2,1 stays in group).
    const int chunk = nt * 4 + wc;
    const int colbase = n0 + wc * 64;
    float bcol[4]; bool bval[4];
#pragma unroll
    for (int ni = 0; ni < 4; ++ni) {
        const int col = colbase + ni * 16 + ml;
        bval[ni] = (col < N_COLS);
        bcol[ni] = bval[ni] ? bias[col] : 0.f;
    }
#pragma unroll
    for (int mi = 0; mi < 8; ++mi) {
        const int rbase = m0 + wr * 128 + (mi >> 2) * 64 + (mi & 3) * 16 + kh * 4;
#pragma unroll
        for (int r = 0; r < 4; ++r) {
            float x[4];
            float bv = -3.0e38f; int bi = 0;
#pragma unroll
            for (int ni = 0; ni < 4; ++ni) {
                x[ni] = acc[mi][ni][r] + bcol[ni];
                const int col = colbase + ni * 16 + ml;
                if (bval[ni] && x[ni] > bv) { bv = x[ni]; bi = col; }
            }
#pragma unroll
            for (int s = 8; s > 0; s >>= 1) {
                const float ov = __shfl_xor(bv, s);
                const int   oi = __shfl_xor(bi, s);
                if (ov > bv || (ov == bv && oi < bi)) { bv = ov; bi = oi; }
            }
            double S = 0.0, T = 0.0;
#pragma unroll
            for (int ni = 0; ni < 4; ++ni) {
                if (bval[ni]) {
                    const float d = x[ni] - bv;         // <= 0
                    const float e = __expf(d);          // HW v_exp_f32
                    S += (double)e;
                    T += (double)(e * d);
                }
            }
#pragma unroll
            for (int s = 8; s > 0; s >>= 1) {
                S += __shfl_xor(S, s);
                T += __shfl_xor(T, s);
            }
            if (ml == 0) {
                double* pp = part + ((size_t)(rbase + r) * 16 + chunk) * 4;
                pp[0] = S; pp[1] = T; pp[2] = (double)bv; pp[3] = (double)bi;
            }
        }
    }
#undef TILE_BODY
#undef MCLM
#undef MCLN
#undef RD_A
#undef RD_B
#undef SB
#undef FRAG
}

// ------------- per-batch: merge partials, stable sort by entropy, tie loop -------------
__global__ __launch_bounds__(64)
void vote_kernel(const double* __restrict__ part, float* __restrict__ out)
{
    __shared__ double e[NUM_TTA];
    __shared__ int    sv[NUM_TTA];
    __shared__ float  counts[N_COLS];

    const int b = blockIdx.x;
    const int t = threadIdx.x;
    const int row = b * NUM_TTA + t;

    // ---- merge 16 chunk partials (ascending chunk = ascending cols) ----
    const double* pp = part + (size_t)row * 64;
    float m = -3.0e38f; int amax = 0;
#pragma unroll
    for (int c = 0; c < 16; ++c) {
        const float pm = (float)pp[c * 4 + 2];
        const int   pa = (int)pp[c * 4 + 3];
        if (pm > m) { m = pm; amax = pa; }   // strict > : earlier chunk (lower col) wins ties
    }
    double S = 0.0, T = 0.0;
#pragma unroll
    for (int c = 0; c < 16; ++c) {
        const double dm = (double)((float)pp[c * 4 + 2]) - (double)m;
        const double f  = exp_neg(dm);
        S += pp[c * 4 + 0] * f;
        T += (pp[c * 4 + 1] + dm * pp[c * 4 + 0]) * f;
    }
    e[t] = log(S) - T / S;
    const int myv = amax;
    for (int c = t; c < N_COLS; c += NUM_TTA) counts[c] = 0.f;
    __syncthreads();

    const double et = e[t];
    int rank = 0;
#pragma unroll
    for (int i = 0; i < NUM_TTA; ++i) {
        const double ei = e[i];
        rank += (ei < et) || (ei == et && i < t);
    }
    sv[rank] = myv;
    __syncthreads();

    if (t == 0) {
        for (int j = 0; j < KEPT; ++j) counts[sv[j]] += 1.f;
        float Mv = 0.f; int Tc = 0;
        for (int j = 0; j < KEPT; ++j) {
            const int c = sv[j];
            bool dup = false;
            for (int q = 0; q < j; ++q) dup = dup || (sv[q] == c);
            if (dup) continue;
            const float cv = counts[c];
            if (cv > Mv) { Mv = cv; Tc = 1; }
            else if (cv == Mv) { Tc += 1; }
        }
        for (int i = 0; i < NUM_TTA - KEPT; ++i) {
            if (Tc <= 1) break;
            const int c = sv[KEPT + i];
            const float oldc = counts[c];
            counts[c] = oldc + 1.f;
            if (oldc == Mv)            { Mv += 1.f; Tc = 1; }
            else if (oldc + 1.f == Mv) { Tc += 1; }
        }
    }
    __syncthreads();

    const size_t o0 = (size_t)b * N_COLS;
    for (int c = t; c < N_COLS; c += NUM_TTA)
        out[o0 + c] = logf(counts[c] * (1.f / 64.f) + 1e-8f);
}

// -------------------------------- launch --------------------------------
extern "C" void kernel_launch(void* const* d_in, const int* in_sizes, int n_in,
                              void* d_out, int out_size, void* d_ws, size_t ws_size,
                              hipStream_t stream) {
    const float* x    = (const float*)d_in[0];
    const float* Wm   = (const float*)d_in[1];
    const float* bias = (const float*)d_in[2];
    float* out = (float*)d_out;

    // ws layout: part f64[16384*16*4] (8 MB) | Wh,Wl bf16[1024*4096]
    char* p = (char*)d_ws;
    double* part = (double*)p;                     p += (size_t)M_ROWS * 16 * 4 * 8;
    unsigned short* Wh = (unsigned short*)p;       p += (size_t)N_PAD * K_DIM * 2;
    unsigned short* Wl = (unsigned short*)p;       p += (size_t)N_PAD * K_DIM * 2;

    split_w<<<dim3(K_DIM / 32, N_PAD / 32), dim3(32, 32), 0, stream>>>(Wm, Wh, Wl);

    const int m_tiles = M_ROWS / 256;   // 64, divisible by 8
    gemm_mfma<<<4 * m_tiles, 512, 0, stream>>>(
        x, Wh, Wl, bias, part, m_tiles);
    vote_kernel<<<BATCH, NUM_TTA, 0, stream>>>(part, out);
}

// Round 12
// 635.219 us; speedup vs baseline: 1.0788x; 1.0072x over previous
//
#include <hip/hip_runtime.h>
#include <cstdint>
#include <cstddef>
#include <math.h>

#define M_ROWS 16384
#define N_COLS 1000
#define N_PAD  1024
#define K_DIM  4096
#define NUM_TTA 64
#define KEPT 6
#define BATCH 256
#define NKT (K_DIM / 32)       // 128 K-tiles of 32

typedef __attribute__((ext_vector_type(8))) short short8;
typedef __attribute__((ext_vector_type(4))) float v4f;

#define GL_LDS16(g, l)                                                        \
    __builtin_amdgcn_global_load_lds(                                         \
        (const __attribute__((address_space(1))) unsigned int*)(g),           \
        (__attribute__((address_space(3))) unsigned int*)(l), 16, 0, 0)

// ---- RNE bf16 split via HW cvt: x = hi + lo (+ ~2^-18 rel) ----
__device__ __forceinline__ void split2(float x, unsigned short& h, unsigned short& l) {
    const __bf16 hb = (__bf16)x;
    const float hf  = (float)hb;
    const __bf16 lb = (__bf16)(x - hf);
    h = __builtin_bit_cast(unsigned short, hb);
    l = __builtin_bit_cast(unsigned short, lb);
}

// 8 floats -> 8 hi bf16 + 8 lo bf16
__device__ __forceinline__ void split8(const float4& a, const float4& b,
                                       short8& hv, short8& lv) {
    unsigned short h, l;
    split2(a.x, h, l); hv[0] = (short)h; lv[0] = (short)l;
    split2(a.y, h, l); hv[1] = (short)h; lv[1] = (short)l;
    split2(a.z, h, l); hv[2] = (short)h; lv[2] = (short)l;
    split2(a.w, h, l); hv[3] = (short)h; lv[3] = (short)l;
    split2(b.x, h, l); hv[4] = (short)h; lv[4] = (short)l;
    split2(b.y, h, l); hv[5] = (short)h; lv[5] = (short)l;
    split2(b.z, h, l); hv[6] = (short)h; lv[6] = (short)l;
    split2(b.w, h, l); hv[7] = (short)h; lv[7] = (short)l;
}

// ---- inline f64 exp for d <= 0 (vote-side merge only; 16 calls/thread) ----
__device__ __forceinline__ double exp_neg(double d) {
    if (d < -700.0) return 0.0;
    const double kd = rint(d * 1.4426950408889634074);
    double r = fma(-kd, 6.93147180369123816490e-01, d);
    r = fma(-kd, 1.90821492927058770002e-10, r);
    double p = 2.08767569878680989792e-09;      // 1/12!
    p = fma(p, r, 2.50521083854417187751e-08);  // 1/11!
    p = fma(p, r, 2.75573192239858906526e-07);  // 1/10!
    p = fma(p, r, 2.75573192239858925110e-06);  // 1/9!
    p = fma(p, r, 2.48015873015873015873e-05);  // 1/8!
    p = fma(p, r, 1.98412698412698412526e-04);  // 1/7!
    p = fma(p, r, 1.38888888888888894069e-03);  // 1/6!
    p = fma(p, r, 8.33333333333333321769e-03);  // 1/5!
    p = fma(p, r, 4.16666666666666643537e-02);  // 1/4!
    p = fma(p, r, 1.66666666666666657415e-01);  // 1/3!
    p = fma(p, r, 5.0e-01);
    p = fma(p, r, 1.0);
    p = fma(p, r, 1.0);
    const long long k = (long long)kd;
    return p * __longlong_as_double((1023LL + k) << 52);
}

// ---------------- W: transpose 4096x1000 -> [n][k] 1024x4096, split ----------------
__global__ __launch_bounds__(1024)
void split_w(const float* __restrict__ W, unsigned short* __restrict__ Wh,
             unsigned short* __restrict__ Wl)
{
    __shared__ float tile[32][33];
    const int k0 = blockIdx.x * 32, n0 = blockIdx.y * 32;
    const int tx = threadIdx.x, ty = threadIdx.y;
    const int n = n0 + tx, k = k0 + ty;
    tile[ty][tx] = (n < N_COLS) ? W[(size_t)k * N_COLS + n] : 0.f;
    __syncthreads();
    const float w = tile[tx][ty];           // = W[k0+tx][n0+ty]
    unsigned short h, l;
    split2(w, h, l);
    const size_t o = (size_t)(n0 + ty) * K_DIM + k0 + tx;
    Wh[o] = h; Wl[o] = l;
}

// ------------- GEMM + fused partial softmax stats -------------
// 256x256 tile, 512 thr = 8 waves (2m x 4n), wave = 128x64 out, BK=32,
// 16x16x32 MFMA, r7's fenced read/MFMA K-loop (measured best).
// Round-12 change: epilogue S/T reduction trees in f32 (store f64).
// Precision: chunk sums <=64 terms, f32 tree err ~5e-7 -> entropy ~5e-6,
// vs min adjacent entropy gap ~1e-4 (64 iid order stats over ~O(1) range).
__global__ __launch_bounds__(512, 2)
void gemm_mfma(const float* __restrict__ X,
               const unsigned short* __restrict__ Bh_, const unsigned short* __restrict__ Bl_,
               const float* __restrict__ bias, double* __restrict__ part,
               int m_tiles)
{
    __shared__ __attribute__((aligned(16))) char smem[2 * 4 * 16384];

    const int t    = threadIdx.x;
    const int lane = t & 63;
    const int wave = t >> 6;
    const int wr   = wave >> 2;        // 0..1  m-half of block tile
    const int wc   = wave & 3;         // 0..3  n-quarter
    const int ml   = lane & 15;
    const int kh   = lane >> 4;        // k-slot (8 bf16 each)

    // ---- XCD swizzle ----
    const int bid  = blockIdx.x;
    const int xcd  = bid & 7;
    const int slot = bid >> 3;
    const int mt   = xcd * (m_tiles >> 3) + (slot >> 2);
    const int nt   = slot & 3;
    const int m0 = mt * 256, n0 = nt * 256;

    // ---- B staging (global_load_lds, pre-swizzled source) ----
    const int    schunk = (t & 3) ^ ((t >> 3) & 3);
    const size_t ro     = (size_t)(t >> 2) * (K_DIM * 2) + (size_t)schunk * 16;
    const char* gBh = (const char*)Bh_ + (size_t)n0 * (K_DIM * 2) + ro;
    const char* gBl = (const char*)Bl_ + (size_t)n0 * (K_DIM * 2) + ro;
    char* ldst = smem + t * 16;
    const size_t RSTEP = (size_t)128 * K_DIM * 2;   // +128 rows

    // ---- A staging (reg path): thread t covers row ar, 16-float half ahalf ----
    const int ar    = t >> 1;          // 0..255
    const int ahalf = t & 1;           // k 0-15 or 16-31 within tile
    const float* gA = X + (size_t)(m0 + ar) * K_DIM + ahalf * 16;
    const int sig = (ar >> 1) & 3;     // row swizzle key (matches reader)
    const int s0  = (ahalf * 2) ^ sig;
    const int s1  = (ahalf * 2 + 1) ^ sig;
    const int aw0 = ar * 64 + (s0 << 4);   // LDS byte off in A panel, floats 0-7
    const int aw1 = ar * 64 + (s1 << 4);   // floats 8-15

    // ---- per-lane LDS read bases (bytes within one 16KB mat panel) ----
    const int swz = ((kh ^ (ml >> 1)) & 3) << 4;
    const int lbA = wr * 8192 + ml * 64 + swz;
    const int lbB = wc * 4096 + ml * 64 + swz;

    v4f acc[8][4];
#pragma unroll
    for (int i = 0; i < 8; ++i)
#pragma unroll
        for (int j = 0; j < 4; ++j) acc[i][j] = (v4f){0.f, 0.f, 0.f, 0.f};

#define FRAG(P) (*(const short8*)(smem + (P)))
#define SB __builtin_amdgcn_sched_barrier(0)

    short8 ah[4], al[4], bh[4], bl[4];

    // ---------------- prologue: stage K-tile 0 into buf 0 ----------------
    {
        const float4 fa = *(const float4*)(gA);
        const float4 fb = *(const float4*)(gA + 4);
        const float4 fc = *(const float4*)(gA + 8);
        const float4 fd = *(const float4*)(gA + 12);
        GL_LDS16(gBh,         ldst + 32768);
        GL_LDS16(gBh + RSTEP, ldst + 40960);
        GL_LDS16(gBl,         ldst + 49152);
        GL_LDS16(gBl + RSTEP, ldst + 57344);
        short8 hv, lv;
        split8(fa, fb, hv, lv);
        *(short8*)(smem + aw0) = hv;
        *(short8*)(smem + 16384 + aw0) = lv;
        split8(fc, fd, hv, lv);
        *(short8*)(smem + aw1) = hv;
        *(short8*)(smem + 16384 + aw1) = lv;
    }
    __syncthreads();

#define RD_B(NF) do {                                                         \
    bh[NF] = FRAG(B0 + 32768 + (NF) * 1024 + lbB);                            \
    bl[NF] = FRAG(B0 + 49152 + (NF) * 1024 + lbB);                            \
} while (0)
#define RD_A(MF, HO) do {                                                     \
    ah[MF] = FRAG(B0 + (HO) +         (MF) * 1024 + lbA);                     \
    al[MF] = FRAG(B0 + (HO) + 16384 + (MF) * 1024 + lbA);                     \
} while (0)
#define MCLN(NF) do {                                                         \
    __builtin_amdgcn_s_setprio(1);                                            \
    _Pragma("unroll")                                                         \
    for (int mf = 0; mf < 4; ++mf)                                            \
        acc[mf][NF] = __builtin_amdgcn_mfma_f32_16x16x32_bf16(ah[mf], bl[NF], acc[mf][NF], 0, 0, 0); \
    _Pragma("unroll")                                                         \
    for (int mf = 0; mf < 4; ++mf)                                            \
        acc[mf][NF] = __builtin_amdgcn_mfma_f32_16x16x32_bf16(al[mf], bh[NF], acc[mf][NF], 0, 0, 0); \
    _Pragma("unroll")                                                         \
    for (int mf = 0; mf < 4; ++mf)                                            \
        acc[mf][NF] = __builtin_amdgcn_mfma_f32_16x16x32_bf16(ah[mf], bh[NF], acc[mf][NF], 0, 0, 0); \
    __builtin_amdgcn_s_setprio(0);                                            \
} while (0)
#define MCLM(MF) do {                                                         \
    __builtin_amdgcn_s_setprio(1);                                            \
    _Pragma("unroll")                                                         \
    for (int nf = 0; nf < 4; ++nf)                                            \
        acc[4 + (MF)][nf] = __builtin_amdgcn_mfma_f32_16x16x32_bf16(ah[MF], bl[nf], acc[4 + (MF)][nf], 0, 0, 0); \
    _Pragma("unroll")                                                         \
    for (int nf = 0; nf < 4; ++nf)                                            \
        acc[4 + (MF)][nf] = __builtin_amdgcn_mfma_f32_16x16x32_bf16(al[MF], bh[nf], acc[4 + (MF)][nf], 0, 0, 0); \
    _Pragma("unroll")                                                         \
    for (int nf = 0; nf < 4; ++nf)                                            \
        acc[4 + (MF)][nf] = __builtin_amdgcn_mfma_f32_16x16x32_bf16(ah[MF], bh[nf], acc[4 + (MF)][nf], 0, 0, 0); \
    __builtin_amdgcn_s_setprio(0);                                            \
} while (0)

#define TILE_BODY(KT, RB) do {                                                \
    const int B0 = (RB) * 65536;                                              \
    const int B1 = ((RB) ^ 1) * 65536;                                        \
    asm volatile("s_waitcnt vmcnt(0) lgkmcnt(0)" ::: "memory");               \
    __builtin_amdgcn_s_barrier();                                             \
    SB;                                                                       \
    const bool pf = (KT) + 1 < NKT;                                           \
    float4 fa, fb;                                                            \
    if (pf) {                                                                 \
        const float* ga_ = gA + ((KT) + 1) * 32;                              \
        fa = *(const float4*)(ga_);                                           \
        fb = *(const float4*)(ga_ + 4);                                       \
        const int kb_ = ((KT) + 1) * 64;                                      \
        GL_LDS16(gBh + kb_,         ldst + B1 + 32768);                       \
        GL_LDS16(gBh + RSTEP + kb_, ldst + B1 + 40960);                       \
        GL_LDS16(gBl + kb_,         ldst + B1 + 49152);                       \
        GL_LDS16(gBl + RSTEP + kb_, ldst + B1 + 57344);                       \
    }                                                                         \
    RD_B(0);                                                                  \
    RD_A(0, 0); RD_A(1, 0); RD_A(2, 0); RD_A(3, 0);                           \
    RD_B(1);                                                                  \
    SB;                                                                       \
    MCLN(0); SB;                                                              \
    RD_B(2); SB;                                                              \
    MCLN(1); SB;                                                              \
    RD_B(3); SB;                                                              \
    MCLN(2); SB;                                                              \
    MCLN(3); SB;                                                              \
    RD_A(0, 4096); RD_A(1, 4096); SB;                                         \
    MCLM(0); SB;                                                              \
    if (pf) {                                                                 \
        short8 hv, lv;                                                        \
        split8(fa, fb, hv, lv);                                               \
        *(short8*)(smem + B1 + aw0) = hv;                                     \
        *(short8*)(smem + B1 + 16384 + aw0) = lv;                             \
        const float* ga_ = gA + ((KT) + 1) * 32 + 8;                          \
        fa = *(const float4*)(ga_);                                           \
        fb = *(const float4*)(ga_ + 4);                                       \
    }                                                                         \
    SB;                                                                       \
    RD_A(2, 4096); SB;                                                        \
    MCLM(1); SB;                                                              \
    RD_A(3, 4096); SB;                                                        \
    MCLM(2); SB;                                                              \
    if (pf) {                                                                 \
        short8 hv, lv;                                                        \
        split8(fa, fb, hv, lv);                                               \
        *(short8*)(smem + B1 + aw1) = hv;                                     \
        *(short8*)(smem + B1 + 16384 + aw1) = lv;                             \
    }                                                                         \
    SB;                                                                       \
    MCLM(3);                                                                  \
} while (0)

#pragma unroll 1
    for (int kt = 0; kt < NKT; kt += 2) {
        TILE_BODY(kt, 0);
        TILE_BODY(kt + 1, 1);
    }

    // ---- fused epilogue: per-(row, chunk) online-softmax partials ----
    // C/D layout: col = lane&15 (ml), row = kh*4 + reg  [m89/m91].
    // chunk = nt*4 + wc covers cols chunk*64 .. +63; stats reduced across
    // the 16-lane half-group (shfl_xor 8,4,2,1 stays in group), f32 trees.
    const int chunk = nt * 4 + wc;
    const int colbase = n0 + wc * 64;
    float bcol[4]; bool bval[4];
#pragma unroll
    for (int ni = 0; ni < 4; ++ni) {
        const int col = colbase + ni * 16 + ml;
        bval[ni] = (col < N_COLS);
        bcol[ni] = bval[ni] ? bias[col] : 0.f;
    }
#pragma unroll
    for (int mi = 0; mi < 8; ++mi) {
        const int rbase = m0 + wr * 128 + (mi >> 2) * 64 + (mi & 3) * 16 + kh * 4;
#pragma unroll
        for (int r = 0; r < 4; ++r) {
            float x[4];
            float bv = -3.0e38f; int bi = 0;
#pragma unroll
            for (int ni = 0; ni < 4; ++ni) {
                x[ni] = acc[mi][ni][r] + bcol[ni];
                const int col = colbase + ni * 16 + ml;
                if (bval[ni] && x[ni] > bv) { bv = x[ni]; bi = col; }
            }
#pragma unroll
            for (int s = 8; s > 0; s >>= 1) {
                const float ov = __shfl_xor(bv, s);
                const int   oi = __shfl_xor(bi, s);
                if (ov > bv || (ov == bv && oi < bi)) { bv = ov; bi = oi; }
            }
            float S = 0.f, T = 0.f;
#pragma unroll
            for (int ni = 0; ni < 4; ++ni) {
                if (bval[ni]) {
                    const float d = x[ni] - bv;         // <= 0
                    const float e = __expf(d);          // HW v_exp_f32
                    S += e;
                    T = fmaf(e, d, T);
                }
            }
#pragma unroll
            for (int s = 8; s > 0; s >>= 1) {
                S += __shfl_xor(S, s);
                T += __shfl_xor(T, s);
            }
            if (ml == 0) {
                double* pp = part + ((size_t)(rbase + r) * 16 + chunk) * 4;
                pp[0] = (double)S; pp[1] = (double)T;
                pp[2] = (double)bv; pp[3] = (double)bi;
            }
        }
    }
#undef TILE_BODY
#undef MCLM
#undef MCLN
#undef RD_A
#undef RD_B
#undef SB
#undef FRAG
}

// ------------- per-batch: merge partials, stable sort by entropy, tie loop -------------
__global__ __launch_bounds__(64)
void vote_kernel(const double* __restrict__ part, float* __restrict__ out)
{
    __shared__ double e[NUM_TTA];
    __shared__ int    sv[NUM_TTA];
    __shared__ float  counts[N_COLS];

    const int b = blockIdx.x;
    const int t = threadIdx.x;
    const int row = b * NUM_TTA + t;

    // ---- merge 16 chunk partials (ascending chunk = ascending cols) ----
    const double* pp = part + (size_t)row * 64;
    float m = -3.0e38f; int amax = 0;
#pragma unroll
    for (int c = 0; c < 16; ++c) {
        const float pm = (float)pp[c * 4 + 2];
        const int   pa = (int)pp[c * 4 + 3];
        if (pm > m) { m = pm; amax = pa; }   // strict > : earlier chunk (lower col) wins ties
    }
    double S = 0.0, T = 0.0;
#pragma unroll
    for (int c = 0; c < 16; ++c) {
        const double dm = (double)((float)pp[c * 4 + 2]) - (double)m;
        const double f  = exp_neg(dm);
        S += pp[c * 4 + 0] * f;
        T += (pp[c * 4 + 1] + dm * pp[c * 4 + 0]) * f;
    }
    e[t] = log(S) - T / S;
    const int myv = amax;
    for (int c = t; c < N_COLS; c += NUM_TTA) counts[c] = 0.f;
    __syncthreads();

    const double et = e[t];
    int rank = 0;
#pragma unroll
    for (int i = 0; i < NUM_TTA; ++i) {
        const double ei = e[i];
        rank += (ei < et) || (ei == et && i < t);
    }
    sv[rank] = myv;
    __syncthreads();

    if (t == 0) {
        for (int j = 0; j < KEPT; ++j) counts[sv[j]] += 1.f;
        float Mv = 0.f; int Tc = 0;
        for (int j = 0; j < KEPT; ++j) {
            const int c = sv[j];
            bool dup = false;
            for (int q = 0; q < j; ++q) dup = dup || (sv[q] == c);
            if (dup) continue;
            const float cv = counts[c];
            if (cv > Mv) { Mv = cv; Tc = 1; }
            else if (cv == Mv) { Tc += 1; }
        }
        for (int i = 0; i < NUM_TTA - KEPT; ++i) {
            if (Tc <= 1) break;
            const int c = sv[KEPT + i];
            const float oldc = counts[c];
            counts[c] = oldc + 1.f;
            if (oldc == Mv)            { Mv += 1.f; Tc = 1; }
            else if (oldc + 1.f == Mv) { Tc += 1; }
        }
    }
    __syncthreads();

    const size_t o0 = (size_t)b * N_COLS;
    for (int c = t; c < N_COLS; c += NUM_TTA)
        out[o0 + c] = logf(counts[c] * (1.f / 64.f) + 1e-8f);
}

// -------------------------------- launch --------------------------------
extern "C" void kernel_launch(void* const* d_in, const int* in_sizes, int n_in,
                              void* d_out, int out_size, void* d_ws, size_t ws_size,
                              hipStream_t stream) {
    const float* x    = (const float*)d_in[0];
    const float* Wm   = (const float*)d_in[1];
    const float* bias = (const float*)d_in[2];
    float* out = (float*)d_out;

    // ws layout: part f64[16384*16*4] (8 MB) | Wh,Wl bf16[1024*4096]
    char* p = (char*)d_ws;
    double* part = (double*)p;                     p += (size_t)M_ROWS * 16 * 4 * 8;
    unsigned short* Wh = (unsigned short*)p;       p += (size_t)N_PAD * K_DIM * 2;
    unsigned short* Wl = (unsigned short*)p;       p += (size_t)N_PAD * K_DIM * 2;

    split_w<<<dim3(K_DIM / 32, N_PAD / 32), dim3(32, 32), 0, stream>>>(Wm, Wh, Wl);

    const int m_tiles = M_ROWS / 256;   // 64, divisible by 8
    gemm_mfma<<<4 * m_tiles, 512, 0, stream>>>(
        x, Wh, Wl, bias, part, m_tiles);
    vote_kernel<<<BATCH, NUM_TTA, 0, stream>>>(part, out);
}